// Round 1
// baseline (409.599 us; speedup 1.0000x reference)
//
#include <hip/hip_runtime.h>
#include <math.h>

#define H 64

// Pass 1: segment max of scores (scores >= 0, so uint-bitpattern atomicMax is a float max)
__global__ void k_score_max(const float* __restrict__ t,
                            const int* __restrict__ dst,
                            unsigned int* __restrict__ m, int E) {
    int i = blockIdx.x * blockDim.x + threadIdx.x;
    int stride = gridDim.x * blockDim.x;
    const float inv = 1.0f / (0.5f + 1e-8f);
    for (; i < E; i += stride) {
        float sc = t[i] * inv;
        atomicMax(&m[dst[i]], __float_as_uint(sc));
    }
}

// Pass 2: e = exp(score - m[dst]); store per-edge e, atomic-add denominator
__global__ void k_exp_sum(const float* __restrict__ t,
                          const int* __restrict__ dst,
                          const float* __restrict__ m,
                          float* __restrict__ s,
                          float* __restrict__ ev, int E) {
    int i = blockIdx.x * blockDim.x + threadIdx.x;
    int stride = gridDim.x * blockDim.x;
    const float inv = 1.0f / (0.5f + 1e-8f);
    for (; i < E; i += stride) {
        int d = dst[i];
        float e = expf(t[i] * inv - m[d]);
        ev[i] = e;
        atomicAdd(&s[d], e);
    }
}

// Pass 3: agg[dst] += alpha * x_src[src]  (wave per edge, lane = feature)
__global__ void k_scatter(const int* __restrict__ src,
                          const int* __restrict__ dst,
                          const float* __restrict__ ev,
                          const float* __restrict__ s,
                          const float* __restrict__ x_src,
                          float* __restrict__ agg, int E) {
    int lane = threadIdx.x & 63;
    int wid = (blockIdx.x * blockDim.x + threadIdx.x) >> 6;
    int nw = (gridDim.x * blockDim.x) >> 6;
    for (int e = wid; e < E; e += nw) {
        int d = dst[e];
        float alpha = ev[e] / (s[d] + 1e-16f);
        int sr = src[e];
        atomicAdd(&agg[d * H + lane], alpha * x_src[sr * H + lane]);
    }
}

// Pass 4: out = agg @ W^T, in-place (row-local). Wave per row; lane j holds W row j
// in registers; agg row broadcast across lanes via shfl.
__global__ __launch_bounds__(256) void k_out_inplace(float* __restrict__ agg,
                                                     const float* __restrict__ W,
                                                     int N) {
    int lane = threadIdx.x & 63;
    float w[H];
#pragma unroll
    for (int k = 0; k < H; ++k) w[k] = W[lane * H + k];
    int wid = (blockIdx.x * blockDim.x + threadIdx.x) >> 6;
    int nw = (gridDim.x * blockDim.x) >> 6;
    for (int n = wid; n < N; n += nw) {
        float a = agg[(size_t)n * H + lane];
        float sum = 0.0f;
#pragma unroll
        for (int k = 0; k < H; ++k) sum += __shfl(a, k, 64) * w[k];
        agg[(size_t)n * H + lane] = sum;  // safe: value read into regs before write
    }
}

extern "C" void kernel_launch(void* const* d_in, const int* in_sizes, int n_in,
                              void* d_out, int out_size, void* d_ws, size_t ws_size,
                              hipStream_t stream) {
    const float* x_src = (const float*)d_in[0];
    // d_in[1] = x_dst (only defines N_DST)
    const float* W = (const float*)d_in[2];
    const int* edge_index = (const int*)d_in[3];
    const float* t = (const float*)d_in[4];

    int E = in_sizes[4];
    int N_DST = in_sizes[1] / H;
    const int* src = edge_index;
    const int* dst = edge_index + E;

    // workspace layout: m[N_DST] (u32), s[N_DST] (f32), ev[E] (f32)
    unsigned int* m = (unsigned int*)d_ws;
    float* s = (float*)d_ws + N_DST;
    float* ev = (float*)d_ws + 2 * (size_t)N_DST;
    float* agg = (float*)d_out;  // agg accumulates in d_out, GEMM is applied in-place

    hipMemsetAsync(d_out, 0, (size_t)N_DST * H * sizeof(float), stream);
    hipMemsetAsync(d_ws, 0, (size_t)(2 * N_DST) * sizeof(float), stream);

    int blocks_e = (E + 255) / 256;
    if (blocks_e > 2048) blocks_e = 2048;

    k_score_max<<<blocks_e, 256, 0, stream>>>(t, dst, m, E);
    k_exp_sum<<<blocks_e, 256, 0, stream>>>(t, dst, (const float*)m, s, ev, E);
    k_scatter<<<2048, 256, 0, stream>>>(src, dst, ev, s, x_src, agg, E);
    k_out_inplace<<<2048, 256, 0, stream>>>(agg, W, N_DST);
}

// Round 2
// 326.571 us; speedup vs baseline: 1.2542x; 1.2542x over previous
//
#include <hip/hip_runtime.h>
#include <math.h>

#define H 64

// ---------- Pass 1: histogram of destinations ----------
__global__ void k_hist(const int* __restrict__ dst, unsigned* __restrict__ cnt, int E) {
    int i = blockIdx.x * blockDim.x + threadIdx.x;
    int st = gridDim.x * blockDim.x;
    for (; i < E; i += st) atomicAdd(&cnt[dst[i]], 1u);
}

// ---------- Hierarchical exclusive scan (3 small kernels) ----------
// A: per-1024-chunk exclusive scan -> base (partial), block totals -> bsum
__global__ __launch_bounds__(1024) void k_scanA(const unsigned* __restrict__ cnt,
                                                unsigned* __restrict__ base,
                                                unsigned* __restrict__ bsum, int N) {
    __shared__ unsigned wsum[16];
    int i = blockIdx.x * 1024 + threadIdx.x;
    unsigned v = (i < N) ? cnt[i] : 0u;
    int lane = threadIdx.x & 63, w = threadIdx.x >> 6;
    unsigned x = v;
#pragma unroll
    for (int off = 1; off < 64; off <<= 1) {
        unsigned y = __shfl_up(x, off, 64);
        if (lane >= off) x += y;
    }
    if (lane == 63) wsum[w] = x;
    __syncthreads();
    if (threadIdx.x < 16) {
        unsigned s = wsum[threadIdx.x];
#pragma unroll
        for (int off = 1; off < 16; off <<= 1) {
            unsigned y = __shfl_up(s, off, 16);
            if ((threadIdx.x & 15) >= off) s += y;
        }
        wsum[threadIdx.x] = s;  // inclusive scan of wave sums
    }
    __syncthreads();
    unsigned wbase = (w > 0) ? wsum[w - 1] : 0u;
    if (i < N) base[i] = wbase + x - v;  // exclusive within block
    if (threadIdx.x == 1023) bsum[blockIdx.x] = wsum[15];
}

// B: single-block exclusive scan of block sums (nb <= 1024)
__global__ __launch_bounds__(1024) void k_scanB(const unsigned* __restrict__ bsum,
                                                unsigned* __restrict__ boff, int nb) {
    __shared__ unsigned wsum[16];
    int i = threadIdx.x;
    unsigned v = (i < nb) ? bsum[i] : 0u;
    int lane = i & 63, w = i >> 6;
    unsigned x = v;
#pragma unroll
    for (int off = 1; off < 64; off <<= 1) {
        unsigned y = __shfl_up(x, off, 64);
        if (lane >= off) x += y;
    }
    if (lane == 63) wsum[w] = x;
    __syncthreads();
    if (i < 16) {
        unsigned s = wsum[i];
#pragma unroll
        for (int off = 1; off < 16; off <<= 1) {
            unsigned y = __shfl_up(s, off, 16);
            if ((i & 15) >= off) s += y;
        }
        wsum[i] = s;
    }
    __syncthreads();
    unsigned wbase = (w > 0) ? wsum[w - 1] : 0u;
    if (i < nb) boff[i] = wbase + x - v;
}

// C: add block offsets; produce final base and cursor copies; base[N] = E
__global__ void k_scanC(unsigned* __restrict__ base, unsigned* __restrict__ cursor,
                        const unsigned* __restrict__ boff, int N, int E) {
    int i = blockIdx.x * blockDim.x + threadIdx.x;
    int st = gridDim.x * blockDim.x;
    for (; i < N; i += st) {
        unsigned b = base[i] + boff[i >> 10];
        base[i] = b;
        cursor[i] = b;
    }
    if (blockIdx.x == 0 && threadIdx.x == 0) base[N] = (unsigned)E;
}

// ---------- Pass 2: bucket edges into CSR order ----------
__global__ void k_permute(const int* __restrict__ dst, unsigned* __restrict__ cursor,
                          int* __restrict__ eidperm, int E) {
    int i = blockIdx.x * blockDim.x + threadIdx.x;
    int st = gridDim.x * blockDim.x;
    for (; i < E; i += st) {
        unsigned pos = atomicAdd(&cursor[dst[i]], 1u);
        eidperm[pos] = i;
    }
}

// ---------- Pass 3: per-destination softmax + weighted gather + fused W GEMM ----------
// One wave per destination row. Lane = output feature.
__global__ __launch_bounds__(256) void k_gather(const unsigned* __restrict__ base,
                                                const int* __restrict__ eidperm,
                                                const int* __restrict__ src,
                                                const float* __restrict__ t,
                                                const float* __restrict__ x_src,
                                                const float* __restrict__ W,
                                                float* __restrict__ out, int N) {
    int lane = threadIdx.x & 63;
    float w[H];
#pragma unroll
    for (int k = 0; k < H; ++k) w[k] = W[lane * H + k];
    int wid = (blockIdx.x * blockDim.x + threadIdx.x) >> 6;
    int nw = (gridDim.x * blockDim.x) >> 6;
    const float inv = 1.0f / (0.5f + 1e-8f);
    for (int d = wid; d < N; d += nw) {
        unsigned r0 = base[d], r1 = base[d + 1];
        int deg = (int)(r1 - r0);
        float acc = 0.0f;
        if (deg > 0) {
            // denominator: sum over exp(score). scores in [0,2): no max needed.
            float ssum = 0.0f;
            for (int c = 0; c < deg; c += 64) {
                int j = c + lane;
                float e = 0.0f;
                if (j < deg) {
                    int eid = eidperm[r0 + j];
                    e = __expf(t[eid] * inv);
                }
#pragma unroll
                for (int off = 32; off >= 1; off >>= 1) e += __shfl_xor(e, off, 64);
                ssum += e;
            }
            float rs = 1.0f / (ssum + 1e-16f);
            // accumulate alpha * x_src[src] into registers
            for (int c = 0; c < deg; c += 64) {
                int j = c + lane;
                int cd = min(64, deg - c);
                float al = 0.0f;
                int sidx = 0;
                if (j < deg) {
                    int eid = eidperm[r0 + j];
                    al = __expf(t[eid] * inv) * rs;
                    sidx = src[eid];
                }
                for (int q = 0; q < cd; ++q) {
                    float a = __shfl(al, q, 64);
                    int sv = __shfl(sidx, q, 64);
                    acc += a * x_src[(size_t)sv * H + lane];
                }
            }
        }
        // fused GEMM: out[d][lane] = sum_k acc_k * W[lane][k]
        float o = 0.0f;
#pragma unroll
        for (int k = 0; k < H; ++k) o += __shfl(acc, k, 64) * w[k];
        out[(size_t)d * H + lane] = o;
    }
}

extern "C" void kernel_launch(void* const* d_in, const int* in_sizes, int n_in,
                              void* d_out, int out_size, void* d_ws, size_t ws_size,
                              hipStream_t stream) {
    const float* x_src = (const float*)d_in[0];
    const float* W = (const float*)d_in[2];
    const int* edge_index = (const int*)d_in[3];
    const float* t = (const float*)d_in[4];

    int E = in_sizes[4];
    int N = in_sizes[1] / H;
    const int* src = edge_index;
    const int* dst = edge_index + E;

    // workspace layout (u32 units): base[N+1] | cursor[N] | bsum[1024] | boff[1024] | eidperm[E]
    unsigned* base = (unsigned*)d_ws;
    unsigned* cursor = base + (size_t)N + 1;
    unsigned* bsum = cursor + N;
    unsigned* boff = bsum + 1024;
    int* eidperm = (int*)(boff + 1024);

    int nb = (N + 1023) / 1024;  // scan chunks (must be <= 1024)

    hipMemsetAsync(cursor, 0, (size_t)N * sizeof(unsigned), stream);

    int blocks_e = (E + 255) / 256;
    if (blocks_e > 2048) blocks_e = 2048;

    k_hist<<<blocks_e, 256, 0, stream>>>(dst, cursor, E);
    k_scanA<<<nb, 1024, 0, stream>>>(cursor, base, bsum, N);
    k_scanB<<<1, 1024, 0, stream>>>(bsum, boff, nb);
    k_scanC<<<512, 256, 0, stream>>>(base, cursor, boff, N, E);
    k_permute<<<blocks_e, 256, 0, stream>>>(dst, cursor, eidperm, E);
    k_gather<<<2560, 256, 0, stream>>>(base, eidperm, src, t, x_src, W, (float*)d_out, N);
}

// Round 3
// 281.971 us; speedup vs baseline: 1.4526x; 1.1582x over previous
//
#include <hip/hip_runtime.h>
#include <math.h>

#define H 64

// ---------- Pass 1: histogram of destinations ----------
__global__ void k_hist(const int* __restrict__ dst, unsigned* __restrict__ cnt, int E) {
    int i = blockIdx.x * blockDim.x + threadIdx.x;
    int st = gridDim.x * blockDim.x;
    for (; i < E; i += st) atomicAdd(&cnt[dst[i]], 1u);
}

// ---------- Hierarchical exclusive scan ----------
__global__ __launch_bounds__(1024) void k_scanA(const unsigned* __restrict__ cnt,
                                                unsigned* __restrict__ base,
                                                unsigned* __restrict__ bsum, int N) {
    __shared__ unsigned wsum[16];
    int i = blockIdx.x * 1024 + threadIdx.x;
    unsigned v = (i < N) ? cnt[i] : 0u;
    int lane = threadIdx.x & 63, w = threadIdx.x >> 6;
    unsigned x = v;
#pragma unroll
    for (int off = 1; off < 64; off <<= 1) {
        unsigned y = __shfl_up(x, off, 64);
        if (lane >= off) x += y;
    }
    if (lane == 63) wsum[w] = x;
    __syncthreads();
    if (threadIdx.x < 16) {
        unsigned s = wsum[threadIdx.x];
#pragma unroll
        for (int off = 1; off < 16; off <<= 1) {
            unsigned y = __shfl_up(s, off, 16);
            if ((threadIdx.x & 15) >= off) s += y;
        }
        wsum[threadIdx.x] = s;
    }
    __syncthreads();
    unsigned wbase = (w > 0) ? wsum[w - 1] : 0u;
    if (i < N) base[i] = wbase + x - v;
    if (threadIdx.x == 1023) bsum[blockIdx.x] = wsum[15];
}

__global__ __launch_bounds__(1024) void k_scanB(const unsigned* __restrict__ bsum,
                                                unsigned* __restrict__ boff, int nb) {
    __shared__ unsigned wsum[16];
    int i = threadIdx.x;
    unsigned v = (i < nb) ? bsum[i] : 0u;
    int lane = i & 63, w = i >> 6;
    unsigned x = v;
#pragma unroll
    for (int off = 1; off < 64; off <<= 1) {
        unsigned y = __shfl_up(x, off, 64);
        if (lane >= off) x += y;
    }
    if (lane == 63) wsum[w] = x;
    __syncthreads();
    if (i < 16) {
        unsigned s = wsum[i];
#pragma unroll
        for (int off = 1; off < 16; off <<= 1) {
            unsigned y = __shfl_up(s, off, 16);
            if ((i & 15) >= off) s += y;
        }
        wsum[i] = s;
    }
    __syncthreads();
    unsigned wbase = (w > 0) ? wsum[w - 1] : 0u;
    if (i < nb) boff[i] = wbase + x - v;
}

__global__ void k_scanC(unsigned* __restrict__ base, unsigned* __restrict__ cursor,
                        const unsigned* __restrict__ boff, int N, int E) {
    int i = blockIdx.x * blockDim.x + threadIdx.x;
    int st = gridDim.x * blockDim.x;
    for (; i < N; i += st) {
        unsigned b = base[i] + boff[i >> 10];
        base[i] = b;
        cursor[i] = b;
    }
    if (blockIdx.x == 0 && threadIdx.x == 0) base[N] = (unsigned)E;
}

// ---------- Pass 2: bucket edges into CSR order, packing (src, exp(score)) ----------
__global__ void k_permute_pack(const int* __restrict__ dst, const int* __restrict__ src,
                               const float* __restrict__ t, unsigned* __restrict__ cursor,
                               int2* __restrict__ payload, int E) {
    const float inv = 1.0f / (0.5f + 1e-8f);
    int i = blockIdx.x * blockDim.x + threadIdx.x;
    int st = gridDim.x * blockDim.x;
    for (; i < E; i += st) {
        unsigned pos = atomicAdd(&cursor[dst[i]], 1u);
        float e = __expf(t[i] * inv);
        payload[pos] = make_int2(src[i], __float_as_int(e));
    }
}

// fallback variant (no payload space): store edge id only
__global__ void k_permute_idx(const int* __restrict__ dst, unsigned* __restrict__ cursor,
                              int* __restrict__ eidperm, int E) {
    int i = blockIdx.x * blockDim.x + threadIdx.x;
    int st = gridDim.x * blockDim.x;
    for (; i < E; i += st) {
        unsigned pos = atomicAdd(&cursor[dst[i]], 1u);
        eidperm[pos] = i;
    }
}

// ---------- Pass 3: single-pass weighted gather + fused W GEMM ----------
// One wave per destination (grid-stride). Lane = feature. 8-way batched gathers for MLP.
__global__ __launch_bounds__(256) void k_gather(const unsigned* __restrict__ base,
                                                const int2* __restrict__ payload,
                                                const float* __restrict__ x_src,
                                                const float* __restrict__ W,
                                                float* __restrict__ out, int N) {
    __shared__ float wt[H * H];  // wt[k*H + j] = W[j*H + k]
    for (int idx = threadIdx.x; idx < H * H; idx += blockDim.x) {
        int j = idx >> 6, k = idx & 63;
        wt[k * H + j] = W[idx];
    }
    __syncthreads();
    int lane = threadIdx.x & 63;
    int wid = (blockIdx.x * blockDim.x + threadIdx.x) >> 6;
    int nw = (gridDim.x * blockDim.x) >> 6;
    for (int d = wid; d < N; d += nw) {
        unsigned r0 = base[d], r1 = base[d + 1];
        int deg = (int)(r1 - r0);
        float acc = 0.0f, ssum = 0.0f;
        for (int c = 0; c < deg; c += 64) {
            int j = c + lane;
            int cd = min(64, deg - c);
            float e = 0.0f;
            int sidx = 0;
            if (j < deg) {
                int2 p = payload[r0 + j];
                sidx = p.x;
                e = __int_as_float(p.y);
            }
            float cs = e;
#pragma unroll
            for (int off = 32; off >= 1; off >>= 1) cs += __shfl_xor(cs, off, 64);
            ssum += cs;
            for (int q = 0; q < cd; q += 8) {
                float a[8];
                int sv[8];
                float v[8];
#pragma unroll
                for (int u = 0; u < 8; ++u) {
                    a[u] = __shfl(e, q + u, 64);      // 0 for padded slots
                    sv[u] = __shfl(sidx, q + u, 64);  // 0 for padded slots (row 0, cached)
                }
#pragma unroll
                for (int u = 0; u < 8; ++u) v[u] = x_src[(size_t)sv[u] * H + lane];
#pragma unroll
                for (int u = 0; u < 8; ++u) acc = fmaf(a[u], v[u], acc);
            }
        }
        acc *= 1.0f / (ssum + 1e-16f);
        float o = 0.0f;
#pragma unroll
        for (int k = 0; k < H; ++k) o = fmaf(__shfl(acc, k, 64), wt[k * H + lane], o);
        out[(size_t)d * H + lane] = o;
    }
}

// fallback: reads src/t through eidperm indirection
__global__ __launch_bounds__(256) void k_gather_idx(const unsigned* __restrict__ base,
                                                    const int* __restrict__ eidperm,
                                                    const int* __restrict__ src,
                                                    const float* __restrict__ t,
                                                    const float* __restrict__ x_src,
                                                    const float* __restrict__ W,
                                                    float* __restrict__ out, int N) {
    __shared__ float wt[H * H];
    for (int idx = threadIdx.x; idx < H * H; idx += blockDim.x) {
        int j = idx >> 6, k = idx & 63;
        wt[k * H + j] = W[idx];
    }
    __syncthreads();
    int lane = threadIdx.x & 63;
    int wid = (blockIdx.x * blockDim.x + threadIdx.x) >> 6;
    int nw = (gridDim.x * blockDim.x) >> 6;
    const float inv = 1.0f / (0.5f + 1e-8f);
    for (int d = wid; d < N; d += nw) {
        unsigned r0 = base[d], r1 = base[d + 1];
        int deg = (int)(r1 - r0);
        float acc = 0.0f, ssum = 0.0f;
        for (int c = 0; c < deg; c += 64) {
            int j = c + lane;
            int cd = min(64, deg - c);
            float e = 0.0f;
            int sidx = 0;
            if (j < deg) {
                int eid = eidperm[r0 + j];
                sidx = src[eid];
                e = __expf(t[eid] * inv);
            }
            float cs = e;
#pragma unroll
            for (int off = 32; off >= 1; off >>= 1) cs += __shfl_xor(cs, off, 64);
            ssum += cs;
            for (int q = 0; q < cd; q += 8) {
                float a[8];
                int sv[8];
                float v[8];
#pragma unroll
                for (int u = 0; u < 8; ++u) {
                    a[u] = __shfl(e, q + u, 64);
                    sv[u] = __shfl(sidx, q + u, 64);
                }
#pragma unroll
                for (int u = 0; u < 8; ++u) v[u] = x_src[(size_t)sv[u] * H + lane];
#pragma unroll
                for (int u = 0; u < 8; ++u) acc = fmaf(a[u], v[u], acc);
            }
        }
        acc *= 1.0f / (ssum + 1e-16f);
        float o = 0.0f;
#pragma unroll
        for (int k = 0; k < H; ++k) o = fmaf(__shfl(acc, k, 64), wt[k * H + lane], o);
        out[(size_t)d * H + lane] = o;
    }
}

extern "C" void kernel_launch(void* const* d_in, const int* in_sizes, int n_in,
                              void* d_out, int out_size, void* d_ws, size_t ws_size,
                              hipStream_t stream) {
    const float* x_src = (const float*)d_in[0];
    const float* W = (const float*)d_in[2];
    const int* edge_index = (const int*)d_in[3];
    const float* t = (const float*)d_in[4];

    int E = in_sizes[4];
    int N = in_sizes[1] / H;
    const int* src = edge_index;
    const int* dst = edge_index + E;

    // ws layout (u32): base[N+1] | cursor[N] | bsum[1024] | boff[1024] | payload(int2)[E]
    unsigned* base = (unsigned*)d_ws;
    unsigned* cursor = base + (size_t)N + 1;
    unsigned* bsum = cursor + N;
    unsigned* boff = bsum + 1024;
    void* tail = (void*)(boff + 1024);
    size_t head_bytes = (size_t)(2 * N + 2049) * 4;
    bool packed = (ws_size >= head_bytes + (size_t)E * 8);

    int nb = (N + 1023) / 1024;

    hipMemsetAsync(cursor, 0, (size_t)N * sizeof(unsigned), stream);

    int blocks_e = (E + 255) / 256;
    if (blocks_e > 2048) blocks_e = 2048;

    k_hist<<<blocks_e, 256, 0, stream>>>(dst, cursor, E);
    k_scanA<<<nb, 1024, 0, stream>>>(cursor, base, bsum, N);
    k_scanB<<<1, 1024, 0, stream>>>(bsum, boff, nb);
    k_scanC<<<512, 256, 0, stream>>>(base, cursor, boff, N, E);
    if (packed) {
        int2* payload = (int2*)tail;
        k_permute_pack<<<blocks_e, 256, 0, stream>>>(dst, src, t, cursor, payload, E);
        k_gather<<<4096, 256, 0, stream>>>(base, payload, x_src, W, (float*)d_out, N);
    } else {
        int* eidperm = (int*)tail;
        k_permute_idx<<<blocks_e, 256, 0, stream>>>(dst, cursor, eidperm, E);
        k_gather_idx<<<4096, 256, 0, stream>>>(base, eidperm, src, t, x_src, W,
                                               (float*)d_out, N);
    }
}

// Round 5
// 268.693 us; speedup vs baseline: 1.5244x; 1.0494x over previous
//
#include <hip/hip_runtime.h>
#include <math.h>

#define H 64

// ---------- Pass 1: histogram of destinations ----------
__global__ void k_hist(const int* __restrict__ dst, unsigned* __restrict__ cnt, int E) {
    int i = blockIdx.x * blockDim.x + threadIdx.x;
    int st = gridDim.x * blockDim.x;
    for (; i < E; i += st) atomicAdd(&cnt[dst[i]], 1u);
}

// ---------- Hierarchical exclusive scan ----------
__global__ __launch_bounds__(1024) void k_scanA(const unsigned* __restrict__ cnt,
                                                unsigned* __restrict__ base,
                                                unsigned* __restrict__ bsum, int N) {
    __shared__ unsigned wsum[16];
    int i = blockIdx.x * 1024 + threadIdx.x;
    unsigned v = (i < N) ? cnt[i] : 0u;
    int lane = threadIdx.x & 63, w = threadIdx.x >> 6;
    unsigned x = v;
#pragma unroll
    for (int off = 1; off < 64; off <<= 1) {
        unsigned y = __shfl_up(x, off, 64);
        if (lane >= off) x += y;
    }
    if (lane == 63) wsum[w] = x;
    __syncthreads();
    if (threadIdx.x < 16) {
        unsigned s = wsum[threadIdx.x];
#pragma unroll
        for (int off = 1; off < 16; off <<= 1) {
            unsigned y = __shfl_up(s, off, 16);
            if ((threadIdx.x & 15) >= off) s += y;
        }
        wsum[threadIdx.x] = s;
    }
    __syncthreads();
    unsigned wbase = (w > 0) ? wsum[w - 1] : 0u;
    if (i < N) base[i] = wbase + x - v;
    if (threadIdx.x == 1023) bsum[blockIdx.x] = wsum[15];
}

__global__ __launch_bounds__(1024) void k_scanB(const unsigned* __restrict__ bsum,
                                                unsigned* __restrict__ boff, int nb) {
    __shared__ unsigned wsum[16];
    int i = threadIdx.x;
    unsigned v = (i < nb) ? bsum[i] : 0u;
    int lane = i & 63, w = i >> 6;
    unsigned x = v;
#pragma unroll
    for (int off = 1; off < 64; off <<= 1) {
        unsigned y = __shfl_up(x, off, 64);
        if (lane >= off) x += y;
    }
    if (lane == 63) wsum[w] = x;
    __syncthreads();
    if (i < 16) {
        unsigned s = wsum[i];
#pragma unroll
        for (int off = 1; off < 16; off <<= 1) {
            unsigned y = __shfl_up(s, off, 16);
            if ((i & 15) >= off) s += y;
        }
        wsum[i] = s;
    }
    __syncthreads();
    unsigned wbase = (w > 0) ? wsum[w - 1] : 0u;
    if (i < nb) boff[i] = wbase + x - v;
}

__global__ void k_scanC(unsigned* __restrict__ base, unsigned* __restrict__ cursor,
                        const unsigned* __restrict__ boff, int N, int E) {
    int i = blockIdx.x * blockDim.x + threadIdx.x;
    int st = gridDim.x * blockDim.x;
    for (; i < N; i += st) {
        unsigned b = base[i] + boff[i >> 10];
        base[i] = b;
        cursor[i] = b;
    }
    if (blockIdx.x == 0 && threadIdx.x == 0) base[N] = (unsigned)E;
}

// ---------- Pass 2: bucket edges into CSR order, packing (src, exp(score)) ----------
__global__ void k_permute_pack(const int* __restrict__ dst, const int* __restrict__ src,
                               const float* __restrict__ t, unsigned* __restrict__ cursor,
                               int2* __restrict__ payload, int E) {
    const float inv = 1.0f / (0.5f + 1e-8f);
    int i = blockIdx.x * blockDim.x + threadIdx.x;
    int st = gridDim.x * blockDim.x;
    for (; i < E; i += st) {
        unsigned pos = atomicAdd(&cursor[dst[i]], 1u);
        float e = __expf(t[i] * inv);
        payload[pos] = make_int2(src[i], __float_as_int(e));
    }
}

__global__ void k_permute_idx(const int* __restrict__ dst, unsigned* __restrict__ cursor,
                              int* __restrict__ eidperm, int E) {
    int i = blockIdx.x * blockDim.x + threadIdx.x;
    int st = gridDim.x * blockDim.x;
    for (; i < E; i += st) {
        unsigned pos = atomicAdd(&cursor[dst[i]], 1u);
        eidperm[pos] = i;
    }
}

// ---------- Pre-transform: y[n][lane] = sum_k x[n][k] * W[lane][k] ----------
// Derived verbatim from R1's k_out_inplace (verified), out-of-place write.
__global__ __launch_bounds__(256) void k_xform(const float* __restrict__ x,
                                               const float* __restrict__ W,
                                               float* __restrict__ y, int M) {
    int lane = threadIdx.x & 63;
    float w[H];
#pragma unroll
    for (int k = 0; k < H; ++k) w[k] = W[lane * H + k];
    int wid = (blockIdx.x * blockDim.x + threadIdx.x) >> 6;
    int nw = (gridDim.x * blockDim.x) >> 6;
    for (int n = wid; n < M; n += nw) {
        float a = x[(size_t)n * H + lane];
        float sum = 0.0f;
#pragma unroll
        for (int k = 0; k < H; ++k) sum = fmaf(__shfl(a, k, 64), w[k], sum);
        y[(size_t)n * H + lane] = sum;
    }
}

// ---------- Pass 3: weighted gather of pre-transformed rows ----------
// Derived verbatim from R3's k_gather (verified): x_src -> y, LDS wt + epilogue deleted.
__global__ __launch_bounds__(256) void k_gather2y(const unsigned* __restrict__ base,
                                                  const int2* __restrict__ payload,
                                                  const float* __restrict__ y,
                                                  float* __restrict__ out, int N) {
    int lane = threadIdx.x & 63;
    int wid = (blockIdx.x * blockDim.x + threadIdx.x) >> 6;
    int nw = (gridDim.x * blockDim.x) >> 6;
    for (int d = wid; d < N; d += nw) {
        unsigned r0 = base[d], r1 = base[d + 1];
        int deg = (int)(r1 - r0);
        float acc = 0.0f, ssum = 0.0f;
        for (int c = 0; c < deg; c += 64) {
            int j = c + lane;
            int cd = min(64, deg - c);
            float e = 0.0f;
            int sidx = 0;
            if (j < deg) {
                int2 p = payload[r0 + j];
                sidx = p.x;
                e = __int_as_float(p.y);
            }
            float cs = e;
#pragma unroll
            for (int off = 32; off >= 1; off >>= 1) cs += __shfl_xor(cs, off, 64);
            ssum += cs;
            for (int q = 0; q < cd; q += 8) {
                float a[8];
                int sv[8];
                float v[8];
#pragma unroll
                for (int u = 0; u < 8; ++u) {
                    a[u] = __shfl(e, q + u, 64);      // 0 for padded slots
                    sv[u] = __shfl(sidx, q + u, 64);  // 0 for padded slots (row 0, cached)
                }
#pragma unroll
                for (int u = 0; u < 8; ++u) v[u] = y[(size_t)sv[u] * H + lane];
#pragma unroll
                for (int u = 0; u < 8; ++u) acc = fmaf(a[u], v[u], acc);
            }
        }
        out[(size_t)d * H + lane] = acc * (1.0f / (ssum + 1e-16f));
    }
}

// ---------- Fallbacks (verified in R2/R3) ----------
__global__ __launch_bounds__(256) void k_gather_fb(const unsigned* __restrict__ base,
                                                   const int2* __restrict__ payload,
                                                   const float* __restrict__ x_src,
                                                   const float* __restrict__ W,
                                                   float* __restrict__ out, int N) {
    __shared__ float wt[H * H];
    for (int idx = threadIdx.x; idx < H * H; idx += blockDim.x) {
        int j = idx >> 6, k = idx & 63;
        wt[k * H + j] = W[idx];
    }
    __syncthreads();
    int lane = threadIdx.x & 63;
    int wid = (blockIdx.x * blockDim.x + threadIdx.x) >> 6;
    int nw = (gridDim.x * blockDim.x) >> 6;
    for (int d = wid; d < N; d += nw) {
        unsigned r0 = base[d], r1 = base[d + 1];
        int deg = (int)(r1 - r0);
        float acc = 0.0f, ssum = 0.0f;
        for (int c = 0; c < deg; c += 64) {
            int j = c + lane;
            int cd = min(64, deg - c);
            float e = 0.0f;
            int sidx = 0;
            if (j < deg) {
                int2 p = payload[r0 + j];
                sidx = p.x;
                e = __int_as_float(p.y);
            }
            float cs = e;
#pragma unroll
            for (int off = 32; off >= 1; off >>= 1) cs += __shfl_xor(cs, off, 64);
            ssum += cs;
            for (int q = 0; q < cd; q += 8) {
                float a[8];
                int sv[8];
                float v[8];
#pragma unroll
                for (int u = 0; u < 8; ++u) {
                    a[u] = __shfl(e, q + u, 64);
                    sv[u] = __shfl(sidx, q + u, 64);
                }
#pragma unroll
                for (int u = 0; u < 8; ++u) v[u] = x_src[(size_t)sv[u] * H + lane];
#pragma unroll
                for (int u = 0; u < 8; ++u) acc = fmaf(a[u], v[u], acc);
            }
        }
        acc *= 1.0f / (ssum + 1e-16f);
        float o = 0.0f;
#pragma unroll
        for (int k = 0; k < H; ++k) o = fmaf(__shfl(acc, k, 64), wt[k * H + lane], o);
        out[(size_t)d * H + lane] = o;
    }
}

__global__ __launch_bounds__(256) void k_gather_idx(const unsigned* __restrict__ base,
                                                    const int* __restrict__ eidperm,
                                                    const int* __restrict__ src,
                                                    const float* __restrict__ t,
                                                    const float* __restrict__ x_src,
                                                    const float* __restrict__ W,
                                                    float* __restrict__ out, int N) {
    __shared__ float wt[H * H];
    for (int idx = threadIdx.x; idx < H * H; idx += blockDim.x) {
        int j = idx >> 6, k = idx & 63;
        wt[k * H + j] = W[idx];
    }
    __syncthreads();
    int lane = threadIdx.x & 63;
    int wid = (blockIdx.x * blockDim.x + threadIdx.x) >> 6;
    int nw = (gridDim.x * blockDim.x) >> 6;
    const float inv = 1.0f / (0.5f + 1e-8f);
    for (int d = wid; d < N; d += nw) {
        unsigned r0 = base[d], r1 = base[d + 1];
        int deg = (int)(r1 - r0);
        float acc = 0.0f, ssum = 0.0f;
        for (int c = 0; c < deg; c += 64) {
            int j = c + lane;
            int cd = min(64, deg - c);
            float e = 0.0f;
            int sidx = 0;
            if (j < deg) {
                int eid = eidperm[r0 + j];
                sidx = src[eid];
                e = __expf(t[eid] * inv);
            }
            float cs = e;
#pragma unroll
            for (int off = 32; off >= 1; off >>= 1) cs += __shfl_xor(cs, off, 64);
            ssum += cs;
            for (int q = 0; q < cd; q += 8) {
                float a[8];
                int sv[8];
                float v[8];
#pragma unroll
                for (int u = 0; u < 8; ++u) {
                    a[u] = __shfl(e, q + u, 64);
                    sv[u] = __shfl(sidx, q + u, 64);
                }
#pragma unroll
                for (int u = 0; u < 8; ++u) v[u] = x_src[(size_t)sv[u] * H + lane];
#pragma unroll
                for (int u = 0; u < 8; ++u) acc = fmaf(a[u], v[u], acc);
            }
        }
        acc *= 1.0f / (ssum + 1e-16f);
        float o = 0.0f;
#pragma unroll
        for (int k = 0; k < H; ++k) o = fmaf(__shfl(acc, k, 64), wt[k * H + lane], o);
        out[(size_t)d * H + lane] = o;
    }
}

extern "C" void kernel_launch(void* const* d_in, const int* in_sizes, int n_in,
                              void* d_out, int out_size, void* d_ws, size_t ws_size,
                              hipStream_t stream) {
    const float* x_src = (const float*)d_in[0];
    const float* W = (const float*)d_in[2];
    const int* edge_index = (const int*)d_in[3];
    const float* t = (const float*)d_in[4];

    int E = in_sizes[4];
    int N = in_sizes[1] / H;  // N_DST
    int M = in_sizes[0] / H;  // N_SRC
    const int* src = edge_index;
    const int* dst = edge_index + E;

    // ws layout (u32): base[N+1] | cursor[N] | bsum[1024] | boff[1024] | payload(int2)[E] | y[M*H]
    unsigned* base = (unsigned*)d_ws;
    unsigned* cursor = base + (size_t)N + 1;
    unsigned* bsum = cursor + N;
    unsigned* boff = bsum + 1024;
    int2* payload = (int2*)(boff + 1024);
    float* y = (float*)(payload + E);

    size_t head_bytes = (size_t)(2 * N + 2049) * 4;
    bool have_payload = (ws_size >= head_bytes + (size_t)E * 8);
    bool have_y = (ws_size >= head_bytes + (size_t)E * 8 + (size_t)M * H * 4);

    int nb = (N + 1023) / 1024;

    hipMemsetAsync(cursor, 0, (size_t)N * sizeof(unsigned), stream);

    int blocks_e = (E + 255) / 256;
    if (blocks_e > 2048) blocks_e = 2048;

    k_hist<<<blocks_e, 256, 0, stream>>>(dst, cursor, E);
    k_scanA<<<nb, 1024, 0, stream>>>(cursor, base, bsum, N);
    k_scanB<<<1, 1024, 0, stream>>>(bsum, boff, nb);
    k_scanC<<<512, 256, 0, stream>>>(base, cursor, boff, N, E);

    if (have_y) {
        k_xform<<<2048, 256, 0, stream>>>(x_src, W, y, M);
        k_permute_pack<<<blocks_e, 256, 0, stream>>>(dst, src, t, cursor, payload, E);
        k_gather2y<<<4096, 256, 0, stream>>>(base, payload, y, (float*)d_out, N);
    } else if (have_payload) {
        k_permute_pack<<<blocks_e, 256, 0, stream>>>(dst, src, t, cursor, payload, E);
        k_gather_fb<<<4096, 256, 0, stream>>>(base, payload, x_src, W, (float*)d_out, N);
    } else {
        int* eidperm = (int*)payload;  // needs only E*4
        k_permute_idx<<<blocks_e, 256, 0, stream>>>(dst, cursor, eidperm, E);
        k_gather_idx<<<4096, 256, 0, stream>>>(base, eidperm, src, t, x_src, W,
                                               (float*)d_out, N);
    }
}

// Round 6
// 235.318 us; speedup vs baseline: 1.7406x; 1.1418x over previous
//
#include <hip/hip_runtime.h>
#include <math.h>

#define H 64
#define NXCD 8

// ---------- Pass 1: histogram of destinations (int4-vectorized reads) ----------
__global__ void k_hist(const int* __restrict__ dst, unsigned* __restrict__ cnt, int E) {
    int i = blockIdx.x * blockDim.x + threadIdx.x;
    int st = gridDim.x * blockDim.x;
    int E4 = E >> 2;
    const int4* d4 = (const int4*)dst;
    for (int k = i; k < E4; k += st) {
        int4 v = d4[k];
        atomicAdd(&cnt[v.x], 1u);
        atomicAdd(&cnt[v.y], 1u);
        atomicAdd(&cnt[v.z], 1u);
        atomicAdd(&cnt[v.w], 1u);
    }
    for (int k = (E4 << 2) + i; k < E; k += st) atomicAdd(&cnt[dst[k]], 1u);
}

// ---------- Hierarchical exclusive scan ----------
__global__ __launch_bounds__(1024) void k_scanA(const unsigned* __restrict__ cnt,
                                                unsigned* __restrict__ base,
                                                unsigned* __restrict__ bsum, int N) {
    __shared__ unsigned wsum[16];
    int i = blockIdx.x * 1024 + threadIdx.x;
    unsigned v = (i < N) ? cnt[i] : 0u;
    int lane = threadIdx.x & 63, w = threadIdx.x >> 6;
    unsigned x = v;
#pragma unroll
    for (int off = 1; off < 64; off <<= 1) {
        unsigned y = __shfl_up(x, off, 64);
        if (lane >= off) x += y;
    }
    if (lane == 63) wsum[w] = x;
    __syncthreads();
    if (threadIdx.x < 16) {
        unsigned s = wsum[threadIdx.x];
#pragma unroll
        for (int off = 1; off < 16; off <<= 1) {
            unsigned y = __shfl_up(s, off, 16);
            if ((threadIdx.x & 15) >= off) s += y;
        }
        wsum[threadIdx.x] = s;
    }
    __syncthreads();
    unsigned wbase = (w > 0) ? wsum[w - 1] : 0u;
    if (i < N) base[i] = wbase + x - v;
    if (threadIdx.x == 1023) bsum[blockIdx.x] = wsum[15];
}

__global__ __launch_bounds__(1024) void k_scanB(const unsigned* __restrict__ bsum,
                                                unsigned* __restrict__ boff, int nb) {
    __shared__ unsigned wsum[16];
    int i = threadIdx.x;
    unsigned v = (i < nb) ? bsum[i] : 0u;
    int lane = i & 63, w = i >> 6;
    unsigned x = v;
#pragma unroll
    for (int off = 1; off < 64; off <<= 1) {
        unsigned y = __shfl_up(x, off, 64);
        if (lane >= off) x += y;
    }
    if (lane == 63) wsum[w] = x;
    __syncthreads();
    if (i < 16) {
        unsigned s = wsum[i];
#pragma unroll
        for (int off = 1; off < 16; off <<= 1) {
            unsigned y = __shfl_up(s, off, 16);
            if ((i & 15) >= off) s += y;
        }
        wsum[i] = s;
    }
    __syncthreads();
    unsigned wbase = (w > 0) ? wsum[w - 1] : 0u;
    if (i < nb) boff[i] = wbase + x - v;
}

__global__ void k_scanC(unsigned* __restrict__ base, unsigned* __restrict__ cursor,
                        const unsigned* __restrict__ boff, int N, int E) {
    int i = blockIdx.x * blockDim.x + threadIdx.x;
    int st = gridDim.x * blockDim.x;
    for (; i < N; i += st) {
        unsigned b = base[i] + boff[i >> 10];
        base[i] = b;
        cursor[i] = b;
    }
    if (blockIdx.x == 0 && threadIdx.x == 0) base[N] = (unsigned)E;
}

// ---------- Pass 2 (fast path): XCD-partitioned CSR bucketing ----------
// Block b (on XCD b%8 under round-robin dispatch) handles dst range b%8 of edge
// slice b/8. All writes to a given payload cache line then come from one XCD,
// so lines assemble fully in its private L2 and stream out once.
__global__ void k_permute_part(const int* __restrict__ dst, const int* __restrict__ src,
                               const float* __restrict__ t, unsigned* __restrict__ cursor,
                               int2* __restrict__ payload, int E, int N) {
    const float inv = 1.0f / (0.5f + 1e-8f);
    int part = blockIdx.x & (NXCD - 1);
    int nslice = gridDim.x >> 3;
    int sblk = blockIdx.x >> 3;
    int lo = (int)((long long)part * N / NXCD);
    int hi = (int)((long long)(part + 1) * N / NXCD);
    int e0 = (int)((long long)sblk * E / nslice);
    int e1 = (int)((long long)(sblk + 1) * E / nslice);
    for (int i = e0 + threadIdx.x; i < e1; i += blockDim.x) {
        int d = dst[i];
        if (d >= lo && d < hi) {
            unsigned pos = atomicAdd(&cursor[d], 1u);
            float e = __expf(t[i] * inv);
            payload[pos] = make_int2(src[i], __float_as_int(e));
        }
    }
}

// ---------- Pass 2 (fallback): plain packing permute ----------
__global__ void k_permute_pack(const int* __restrict__ dst, const int* __restrict__ src,
                               const float* __restrict__ t, unsigned* __restrict__ cursor,
                               int2* __restrict__ payload, int E) {
    const float inv = 1.0f / (0.5f + 1e-8f);
    int i = blockIdx.x * blockDim.x + threadIdx.x;
    int st = gridDim.x * blockDim.x;
    for (; i < E; i += st) {
        unsigned pos = atomicAdd(&cursor[dst[i]], 1u);
        float e = __expf(t[i] * inv);
        payload[pos] = make_int2(src[i], __float_as_int(e));
    }
}

__global__ void k_permute_idx(const int* __restrict__ dst, unsigned* __restrict__ cursor,
                              int* __restrict__ eidperm, int E) {
    int i = blockIdx.x * blockDim.x + threadIdx.x;
    int st = gridDim.x * blockDim.x;
    for (; i < E; i += st) {
        unsigned pos = atomicAdd(&cursor[dst[i]], 1u);
        eidperm[pos] = i;
    }
}

// ---------- Pre-transform: y[n][lane] = sum_k x[n][k] * W[lane][k] ----------
__global__ __launch_bounds__(256) void k_xform(const float* __restrict__ x,
                                               const float* __restrict__ W,
                                               float* __restrict__ y, int M) {
    int lane = threadIdx.x & 63;
    float w[H];
#pragma unroll
    for (int k = 0; k < H; ++k) w[k] = W[lane * H + k];
    int wid = (blockIdx.x * blockDim.x + threadIdx.x) >> 6;
    int nw = (gridDim.x * blockDim.x) >> 6;
    for (int n = wid; n < M; n += nw) {
        float a = x[(size_t)n * H + lane];
        float sum = 0.0f;
#pragma unroll
        for (int k = 0; k < H; ++k) sum = fmaf(__shfl(a, k, 64), w[k], sum);
        y[(size_t)n * H + lane] = sum;
    }
}

// ---------- Pass 3: weighted gather of pre-transformed rows (verified R5) ----------
__global__ __launch_bounds__(256) void k_gather2y(const unsigned* __restrict__ base,
                                                  const int2* __restrict__ payload,
                                                  const float* __restrict__ y,
                                                  float* __restrict__ out, int N) {
    int lane = threadIdx.x & 63;
    int wid = (blockIdx.x * blockDim.x + threadIdx.x) >> 6;
    int nw = (gridDim.x * blockDim.x) >> 6;
    for (int d = wid; d < N; d += nw) {
        unsigned r0 = base[d], r1 = base[d + 1];
        int deg = (int)(r1 - r0);
        float acc = 0.0f, ssum = 0.0f;
        for (int c = 0; c < deg; c += 64) {
            int j = c + lane;
            int cd = min(64, deg - c);
            float e = 0.0f;
            int sidx = 0;
            if (j < deg) {
                int2 p = payload[r0 + j];
                sidx = p.x;
                e = __int_as_float(p.y);
            }
            float cs = e;
#pragma unroll
            for (int off = 32; off >= 1; off >>= 1) cs += __shfl_xor(cs, off, 64);
            ssum += cs;
            for (int q = 0; q < cd; q += 8) {
                float a[8];
                int sv[8];
                float v[8];
#pragma unroll
                for (int u = 0; u < 8; ++u) {
                    a[u] = __shfl(e, q + u, 64);      // 0 for padded slots
                    sv[u] = __shfl(sidx, q + u, 64);  // 0 for padded slots (row 0, hot)
                }
#pragma unroll
                for (int u = 0; u < 8; ++u) v[u] = y[(size_t)sv[u] * H + lane];
#pragma unroll
                for (int u = 0; u < 8; ++u) acc = fmaf(a[u], v[u], acc);
            }
        }
        out[(size_t)d * H + lane] = acc * (1.0f / (ssum + 1e-16f));
    }
}

// ---------- Fallbacks (verified in R2/R3) ----------
__global__ __launch_bounds__(256) void k_gather_fb(const unsigned* __restrict__ base,
                                                   const int2* __restrict__ payload,
                                                   const float* __restrict__ x_src,
                                                   const float* __restrict__ W,
                                                   float* __restrict__ out, int N) {
    __shared__ float wt[H * H];
    for (int idx = threadIdx.x; idx < H * H; idx += blockDim.x) {
        int j = idx >> 6, k = idx & 63;
        wt[k * H + j] = W[idx];
    }
    __syncthreads();
    int lane = threadIdx.x & 63;
    int wid = (blockIdx.x * blockDim.x + threadIdx.x) >> 6;
    int nw = (gridDim.x * blockDim.x) >> 6;
    for (int d = wid; d < N; d += nw) {
        unsigned r0 = base[d], r1 = base[d + 1];
        int deg = (int)(r1 - r0);
        float acc = 0.0f, ssum = 0.0f;
        for (int c = 0; c < deg; c += 64) {
            int j = c + lane;
            int cd = min(64, deg - c);
            float e = 0.0f;
            int sidx = 0;
            if (j < deg) {
                int2 p = payload[r0 + j];
                sidx = p.x;
                e = __int_as_float(p.y);
            }
            float cs = e;
#pragma unroll
            for (int off = 32; off >= 1; off >>= 1) cs += __shfl_xor(cs, off, 64);
            ssum += cs;
            for (int q = 0; q < cd; q += 8) {
                float a[8];
                int sv[8];
                float v[8];
#pragma unroll
                for (int u = 0; u < 8; ++u) {
                    a[u] = __shfl(e, q + u, 64);
                    sv[u] = __shfl(sidx, q + u, 64);
                }
#pragma unroll
                for (int u = 0; u < 8; ++u) v[u] = x_src[(size_t)sv[u] * H + lane];
#pragma unroll
                for (int u = 0; u < 8; ++u) acc = fmaf(a[u], v[u], acc);
            }
        }
        acc *= 1.0f / (ssum + 1e-16f);
        float o = 0.0f;
#pragma unroll
        for (int k = 0; k < H; ++k) o = fmaf(__shfl(acc, k, 64), wt[k * H + lane], o);
        out[(size_t)d * H + lane] = o;
    }
}

__global__ __launch_bounds__(256) void k_gather_idx(const unsigned* __restrict__ base,
                                                    const int* __restrict__ eidperm,
                                                    const int* __restrict__ src,
                                                    const float* __restrict__ t,
                                                    const float* __restrict__ x_src,
                                                    const float* __restrict__ W,
                                                    float* __restrict__ out, int N) {
    __shared__ float wt[H * H];
    for (int idx = threadIdx.x; idx < H * H; idx += blockDim.x) {
        int j = idx >> 6, k = idx & 63;
        wt[k * H + j] = W[idx];
    }
    __syncthreads();
    int lane = threadIdx.x & 63;
    int wid = (blockIdx.x * blockDim.x + threadIdx.x) >> 6;
    int nw = (gridDim.x * blockDim.x) >> 6;
    const float inv = 1.0f / (0.5f + 1e-8f);
    for (int d = wid; d < N; d += nw) {
        unsigned r0 = base[d], r1 = base[d + 1];
        int deg = (int)(r1 - r0);
        float acc = 0.0f, ssum = 0.0f;
        for (int c = 0; c < deg; c += 64) {
            int j = c + lane;
            int cd = min(64, deg - c);
            float e = 0.0f;
            int sidx = 0;
            if (j < deg) {
                int eid = eidperm[r0 + j];
                sidx = src[eid];
                e = __expf(t[eid] * inv);
            }
            float cs = e;
#pragma unroll
            for (int off = 32; off >= 1; off >>= 1) cs += __shfl_xor(cs, off, 64);
            ssum += cs;
            for (int q = 0; q < cd; q += 8) {
                float a[8];
                int sv[8];
                float v[8];
#pragma unroll
                for (int u = 0; u < 8; ++u) {
                    a[u] = __shfl(e, q + u, 64);
                    sv[u] = __shfl(sidx, q + u, 64);
                }
#pragma unroll
                for (int u = 0; u < 8; ++u) v[u] = x_src[(size_t)sv[u] * H + lane];
#pragma unroll
                for (int u = 0; u < 8; ++u) acc = fmaf(a[u], v[u], acc);
            }
        }
        acc *= 1.0f / (ssum + 1e-16f);
        float o = 0.0f;
#pragma unroll
        for (int k = 0; k < H; ++k) o = fmaf(__shfl(acc, k, 64), wt[k * H + lane], o);
        out[(size_t)d * H + lane] = o;
    }
}

extern "C" void kernel_launch(void* const* d_in, const int* in_sizes, int n_in,
                              void* d_out, int out_size, void* d_ws, size_t ws_size,
                              hipStream_t stream) {
    const float* x_src = (const float*)d_in[0];
    const float* W = (const float*)d_in[2];
    const int* edge_index = (const int*)d_in[3];
    const float* t = (const float*)d_in[4];

    int E = in_sizes[4];
    int N = in_sizes[1] / H;  // N_DST
    int M = in_sizes[0] / H;  // N_SRC
    const int* src = edge_index;
    const int* dst = edge_index + E;

    // ws layout (u32): base[N+1] | cursor[N] | bsum[1024] | boff[1024] | payload(int2)[E] | y[M*H]
    unsigned* base = (unsigned*)d_ws;
    unsigned* cursor = base + (size_t)N + 1;
    unsigned* bsum = cursor + N;
    unsigned* boff = bsum + 1024;
    int2* payload = (int2*)(boff + 1024);
    float* y = (float*)(payload + E);

    size_t head_bytes = (size_t)(2 * N + 2049) * 4;
    bool have_payload = (ws_size >= head_bytes + (size_t)E * 8);
    bool have_y = (ws_size >= head_bytes + (size_t)E * 8 + (size_t)M * H * 4);

    int nb = (N + 1023) / 1024;

    hipMemsetAsync(cursor, 0, (size_t)N * sizeof(unsigned), stream);

    int blocks_e = (E + 255) / 256;
    if (blocks_e > 2048) blocks_e = 2048;

    k_hist<<<1024, 256, 0, stream>>>(dst, cursor, E);
    k_scanA<<<nb, 1024, 0, stream>>>(cursor, base, bsum, N);
    k_scanB<<<1, 1024, 0, stream>>>(bsum, boff, nb);
    k_scanC<<<512, 256, 0, stream>>>(base, cursor, boff, N, E);

    if (have_y) {
        k_xform<<<2048, 256, 0, stream>>>(x_src, W, y, M);
        k_permute_part<<<2048, 256, 0, stream>>>(dst, src, t, cursor, payload, E, N);
        k_gather2y<<<4096, 256, 0, stream>>>(base, payload, y, (float*)d_out, N);
    } else if (have_payload) {
        k_permute_pack<<<blocks_e, 256, 0, stream>>>(dst, src, t, cursor, payload, E);
        k_gather_fb<<<4096, 256, 0, stream>>>(base, payload, x_src, W, (float*)d_out, N);
    } else {
        int* eidperm = (int*)payload;  // needs only E*4
        k_permute_idx<<<blocks_e, 256, 0, stream>>>(dst, cursor, eidperm, E);
        k_gather_idx<<<4096, 256, 0, stream>>>(base, eidperm, src, t, x_src, W,
                                               (float*)d_out, N);
    }
}

// Round 7
// 201.948 us; speedup vs baseline: 2.0282x; 1.1652x over previous
//
#include <hip/hip_runtime.h>
#include <math.h>

#define H 64
#define NXCD 8

// ---------- Pass 1: histogram of destinations (int4-vectorized reads) ----------
__global__ void k_hist(const int* __restrict__ dst, unsigned* __restrict__ cnt, int E) {
    int i = blockIdx.x * blockDim.x + threadIdx.x;
    int st = gridDim.x * blockDim.x;
    int E4 = E >> 2;
    const int4* d4 = (const int4*)dst;
    for (int k = i; k < E4; k += st) {
        int4 v = d4[k];
        atomicAdd(&cnt[v.x], 1u);
        atomicAdd(&cnt[v.y], 1u);
        atomicAdd(&cnt[v.z], 1u);
        atomicAdd(&cnt[v.w], 1u);
    }
    for (int k = (E4 << 2) + i; k < E; k += st) atomicAdd(&cnt[dst[k]], 1u);
}

// ---------- Hierarchical exclusive scan ----------
__global__ __launch_bounds__(1024) void k_scanA(const unsigned* __restrict__ cnt,
                                                unsigned* __restrict__ base,
                                                unsigned* __restrict__ bsum, int N) {
    __shared__ unsigned wsum[16];
    int i = blockIdx.x * 1024 + threadIdx.x;
    unsigned v = (i < N) ? cnt[i] : 0u;
    int lane = threadIdx.x & 63, w = threadIdx.x >> 6;
    unsigned x = v;
#pragma unroll
    for (int off = 1; off < 64; off <<= 1) {
        unsigned y = __shfl_up(x, off, 64);
        if (lane >= off) x += y;
    }
    if (lane == 63) wsum[w] = x;
    __syncthreads();
    if (threadIdx.x < 16) {
        unsigned s = wsum[threadIdx.x];
#pragma unroll
        for (int off = 1; off < 16; off <<= 1) {
            unsigned y = __shfl_up(s, off, 16);
            if ((threadIdx.x & 15) >= off) s += y;
        }
        wsum[threadIdx.x] = s;
    }
    __syncthreads();
    unsigned wbase = (w > 0) ? wsum[w - 1] : 0u;
    if (i < N) base[i] = wbase + x - v;
    if (threadIdx.x == 1023) bsum[blockIdx.x] = wsum[15];
}

__global__ __launch_bounds__(1024) void k_scanB(const unsigned* __restrict__ bsum,
                                                unsigned* __restrict__ boff, int nb) {
    __shared__ unsigned wsum[16];
    int i = threadIdx.x;
    unsigned v = (i < nb) ? bsum[i] : 0u;
    int lane = i & 63, w = i >> 6;
    unsigned x = v;
#pragma unroll
    for (int off = 1; off < 64; off <<= 1) {
        unsigned y = __shfl_up(x, off, 64);
        if (lane >= off) x += y;
    }
    if (lane == 63) wsum[w] = x;
    __syncthreads();
    if (i < 16) {
        unsigned s = wsum[i];
#pragma unroll
        for (int off = 1; off < 16; off <<= 1) {
            unsigned y = __shfl_up(s, off, 16);
            if ((i & 15) >= off) s += y;
        }
        wsum[i] = s;
    }
    __syncthreads();
    unsigned wbase = (w > 0) ? wsum[w - 1] : 0u;
    if (i < nb) boff[i] = wbase + x - v;
}

__global__ void k_scanC(unsigned* __restrict__ base, unsigned* __restrict__ cursor,
                        const unsigned* __restrict__ boff, int N, int E) {
    int i = blockIdx.x * blockDim.x + threadIdx.x;
    int st = gridDim.x * blockDim.x;
    for (; i < N; i += st) {
        unsigned b = base[i] + boff[i >> 10];
        base[i] = b;
        cursor[i] = b;
    }
    if (blockIdx.x == 0 && threadIdx.x == 0) base[N] = (unsigned)E;
}

// ---------- Pass 2 (fast path): XCD-partitioned CSR bucketing (verified R6) ----------
__global__ void k_permute_part(const int* __restrict__ dst, const int* __restrict__ src,
                               const float* __restrict__ t, unsigned* __restrict__ cursor,
                               int2* __restrict__ payload, int E, int N) {
    const float inv = 1.0f / (0.5f + 1e-8f);
    int part = blockIdx.x & (NXCD - 1);
    int nslice = gridDim.x >> 3;
    int sblk = blockIdx.x >> 3;
    int lo = (int)((long long)part * N / NXCD);
    int hi = (int)((long long)(part + 1) * N / NXCD);
    int e0 = (int)((long long)sblk * E / nslice);
    int e1 = (int)((long long)(sblk + 1) * E / nslice);
    for (int i = e0 + threadIdx.x; i < e1; i += blockDim.x) {
        int d = dst[i];
        if (d >= lo && d < hi) {
            unsigned pos = atomicAdd(&cursor[d], 1u);
            float e = __expf(t[i] * inv);
            payload[pos] = make_int2(src[i], __float_as_int(e));
        }
    }
}

// ---------- Pass 2 (fallback): plain packing permute ----------
__global__ void k_permute_pack(const int* __restrict__ dst, const int* __restrict__ src,
                               const float* __restrict__ t, unsigned* __restrict__ cursor,
                               int2* __restrict__ payload, int E) {
    const float inv = 1.0f / (0.5f + 1e-8f);
    int i = blockIdx.x * blockDim.x + threadIdx.x;
    int st = gridDim.x * blockDim.x;
    for (; i < E; i += st) {
        unsigned pos = atomicAdd(&cursor[dst[i]], 1u);
        float e = __expf(t[i] * inv);
        payload[pos] = make_int2(src[i], __float_as_int(e));
    }
}

__global__ void k_permute_idx(const int* __restrict__ dst, unsigned* __restrict__ cursor,
                              int* __restrict__ eidperm, int E) {
    int i = blockIdx.x * blockDim.x + threadIdx.x;
    int st = gridDim.x * blockDim.x;
    for (; i < E; i += st) {
        unsigned pos = atomicAdd(&cursor[dst[i]], 1u);
        eidperm[pos] = i;
    }
}

// ---------- Pre-transform: y = x @ W^T, tiled 64-row blocks, 4x4 register tile ----------
// y[n][c] = sum_k x[n][k] * W[c][k].
// LDS: xs[r][k] = x[row0+r][k]  (row-major, pad 68 -> 16B-aligned rows)
//      wT[k][c] = W[c][k]
__global__ __launch_bounds__(256) void k_xform2(const float* __restrict__ x,
                                                const float* __restrict__ W,
                                                float* __restrict__ y, int M) {
    __shared__ float xs[64][68];
    __shared__ float wT[64][68];
    int t = threadIdx.x;
    int row0 = blockIdx.x * 64;
#pragma unroll
    for (int i = 0; i < 4; ++i) {
        int pos = t * 4 + i * 1024;       // multiple of 4, covers [0,4096)
        int r = pos >> 6, k = pos & 63;   // k multiple of 4
        int gr = row0 + r;
        float4 v = (gr < M) ? *(const float4*)&x[(size_t)gr * H + k]
                            : make_float4(0.f, 0.f, 0.f, 0.f);
        *(float4*)&xs[r][k] = v;          // xs[r][k..k+3] = x[gr][k..k+3]
        float4 wv = *(const float4*)&W[pos];  // = W[c=r][k..k+3]
        wT[k + 0][r] = wv.x;
        wT[k + 1][r] = wv.y;
        wT[k + 2][r] = wv.z;
        wT[k + 3][r] = wv.w;
    }
    __syncthreads();
    int tx = t & 15, ty = t >> 4;  // cols tx*4.., rows ty*4..
    float accm[4][4] = {};
#pragma unroll
    for (int k0 = 0; k0 < H; k0 += 4) {
        float4 b0 = *(const float4*)&wT[k0 + 0][tx * 4];
        float4 b1 = *(const float4*)&wT[k0 + 1][tx * 4];
        float4 b2 = *(const float4*)&wT[k0 + 2][tx * 4];
        float4 b3 = *(const float4*)&wT[k0 + 3][tx * 4];
#pragma unroll
        for (int i = 0; i < 4; ++i) {
            float4 a = *(const float4*)&xs[ty * 4 + i][k0];  // x[row][k0..k0+3]
            accm[i][0] = fmaf(a.x, b0.x, fmaf(a.y, b1.x, fmaf(a.z, b2.x, fmaf(a.w, b3.x, accm[i][0]))));
            accm[i][1] = fmaf(a.x, b0.y, fmaf(a.y, b1.y, fmaf(a.z, b2.y, fmaf(a.w, b3.y, accm[i][1]))));
            accm[i][2] = fmaf(a.x, b0.z, fmaf(a.y, b1.z, fmaf(a.z, b2.z, fmaf(a.w, b3.z, accm[i][2]))));
            accm[i][3] = fmaf(a.x, b0.w, fmaf(a.y, b1.w, fmaf(a.z, b2.w, fmaf(a.w, b3.w, accm[i][3]))));
        }
    }
#pragma unroll
    for (int i = 0; i < 4; ++i) {
        int gr = row0 + ty * 4 + i;
        if (gr < M) {
            float4 o = make_float4(accm[i][0], accm[i][1], accm[i][2], accm[i][3]);
            *(float4*)&y[(size_t)gr * H + tx * 4] = o;
        }
    }
}

// Slow-but-verified fallback xform (R5/R6)
__global__ __launch_bounds__(256) void k_xform(const float* __restrict__ x,
                                               const float* __restrict__ W,
                                               float* __restrict__ y, int M) {
    int lane = threadIdx.x & 63;
    float w[H];
#pragma unroll
    for (int k = 0; k < H; ++k) w[k] = W[lane * H + k];
    int wid = (blockIdx.x * blockDim.x + threadIdx.x) >> 6;
    int nw = (gridDim.x * blockDim.x) >> 6;
    for (int n = wid; n < M; n += nw) {
        float a = x[(size_t)n * H + lane];
        float sum = 0.0f;
#pragma unroll
        for (int k = 0; k < H; ++k) sum = fmaf(__shfl(a, k, 64), w[k], sum);
        y[(size_t)n * H + lane] = sum;
    }
}

// ---------- Pass 3: weighted gather of pre-transformed rows (verified R5/R6) ----------
__global__ __launch_bounds__(256) void k_gather2y(const unsigned* __restrict__ base,
                                                  const int2* __restrict__ payload,
                                                  const float* __restrict__ y,
                                                  float* __restrict__ out, int N) {
    int lane = threadIdx.x & 63;
    int wid = (blockIdx.x * blockDim.x + threadIdx.x) >> 6;
    int nw = (gridDim.x * blockDim.x) >> 6;
    for (int d = wid; d < N; d += nw) {
        unsigned r0 = base[d], r1 = base[d + 1];
        int deg = (int)(r1 - r0);
        float acc = 0.0f, ssum = 0.0f;
        for (int c = 0; c < deg; c += 64) {
            int j = c + lane;
            int cd = min(64, deg - c);
            float e = 0.0f;
            int sidx = 0;
            if (j < deg) {
                int2 p = payload[r0 + j];
                sidx = p.x;
                e = __int_as_float(p.y);
            }
            float cs = e;
#pragma unroll
            for (int off = 32; off >= 1; off >>= 1) cs += __shfl_xor(cs, off, 64);
            ssum += cs;
            for (int q = 0; q < cd; q += 8) {
                float a[8];
                int sv[8];
                float v[8];
#pragma unroll
                for (int u = 0; u < 8; ++u) {
                    a[u] = __shfl(e, q + u, 64);      // 0 for padded slots
                    sv[u] = __shfl(sidx, q + u, 64);  // 0 for padded slots (row 0, hot)
                }
#pragma unroll
                for (int u = 0; u < 8; ++u) v[u] = y[(size_t)sv[u] * H + lane];
#pragma unroll
                for (int u = 0; u < 8; ++u) acc = fmaf(a[u], v[u], acc);
            }
        }
        out[(size_t)d * H + lane] = acc * (1.0f / (ssum + 1e-16f));
    }
}

// ---------- Fallbacks (verified in R2/R3) ----------
__global__ __launch_bounds__(256) void k_gather_fb(const unsigned* __restrict__ base,
                                                   const int2* __restrict__ payload,
                                                   const float* __restrict__ x_src,
                                                   const float* __restrict__ W,
                                                   float* __restrict__ out, int N) {
    __shared__ float wt[H * H];
    for (int idx = threadIdx.x; idx < H * H; idx += blockDim.x) {
        int j = idx >> 6, k = idx & 63;
        wt[k * H + j] = W[idx];
    }
    __syncthreads();
    int lane = threadIdx.x & 63;
    int wid = (blockIdx.x * blockDim.x + threadIdx.x) >> 6;
    int nw = (gridDim.x * blockDim.x) >> 6;
    for (int d = wid; d < N; d += nw) {
        unsigned r0 = base[d], r1 = base[d + 1];
        int deg = (int)(r1 - r0);
        float acc = 0.0f, ssum = 0.0f;
        for (int c = 0; c < deg; c += 64) {
            int j = c + lane;
            int cd = min(64, deg - c);
            float e = 0.0f;
            int sidx = 0;
            if (j < deg) {
                int2 p = payload[r0 + j];
                sidx = p.x;
                e = __int_as_float(p.y);
            }
            float cs = e;
#pragma unroll
            for (int off = 32; off >= 1; off >>= 1) cs += __shfl_xor(cs, off, 64);
            ssum += cs;
            for (int q = 0; q < cd; q += 8) {
                float a[8];
                int sv[8];
                float v[8];
#pragma unroll
                for (int u = 0; u < 8; ++u) {
                    a[u] = __shfl(e, q + u, 64);
                    sv[u] = __shfl(sidx, q + u, 64);
                }
#pragma unroll
                for (int u = 0; u < 8; ++u) v[u] = x_src[(size_t)sv[u] * H + lane];
#pragma unroll
                for (int u = 0; u < 8; ++u) acc = fmaf(a[u], v[u], acc);
            }
        }
        acc *= 1.0f / (ssum + 1e-16f);
        float o = 0.0f;
#pragma unroll
        for (int k = 0; k < H; ++k) o = fmaf(__shfl(acc, k, 64), wt[k * H + lane], o);
        out[(size_t)d * H + lane] = o;
    }
}

__global__ __launch_bounds__(256) void k_gather_idx(const unsigned* __restrict__ base,
                                                    const int* __restrict__ eidperm,
                                                    const int* __restrict__ src,
                                                    const float* __restrict__ t,
                                                    const float* __restrict__ x_src,
                                                    const float* __restrict__ W,
                                                    float* __restrict__ out, int N) {
    __shared__ float wt[H * H];
    for (int idx = threadIdx.x; idx < H * H; idx += blockDim.x) {
        int j = idx >> 6, k = idx & 63;
        wt[k * H + j] = W[idx];
    }
    __syncthreads();
    int lane = threadIdx.x & 63;
    int wid = (blockIdx.x * blockDim.x + threadIdx.x) >> 6;
    int nw = (gridDim.x * blockDim.x) >> 6;
    const float inv = 1.0f / (0.5f + 1e-8f);
    for (int d = wid; d < N; d += nw) {
        unsigned r0 = base[d], r1 = base[d + 1];
        int deg = (int)(r1 - r0);
        float acc = 0.0f, ssum = 0.0f;
        for (int c = 0; c < deg; c += 64) {
            int j = c + lane;
            int cd = min(64, deg - c);
            float e = 0.0f;
            int sidx = 0;
            if (j < deg) {
                int eid = eidperm[r0 + j];
                sidx = src[eid];
                e = __expf(t[eid] * inv);
            }
            float cs = e;
#pragma unroll
            for (int off = 32; off >= 1; off >>= 1) cs += __shfl_xor(cs, off, 64);
            ssum += cs;
            for (int q = 0; q < cd; q += 8) {
                float a[8];
                int sv[8];
                float v[8];
#pragma unroll
                for (int u = 0; u < 8; ++u) {
                    a[u] = __shfl(e, q + u, 64);
                    sv[u] = __shfl(sidx, q + u, 64);
                }
#pragma unroll
                for (int u = 0; u < 8; ++u) v[u] = x_src[(size_t)sv[u] * H + lane];
#pragma unroll
                for (int u = 0; u < 8; ++u) acc = fmaf(a[u], v[u], acc);
            }
        }
        acc *= 1.0f / (ssum + 1e-16f);
        float o = 0.0f;
#pragma unroll
        for (int k = 0; k < H; ++k) o = fmaf(__shfl(acc, k, 64), wt[k * H + lane], o);
        out[(size_t)d * H + lane] = o;
    }
}

extern "C" void kernel_launch(void* const* d_in, const int* in_sizes, int n_in,
                              void* d_out, int out_size, void* d_ws, size_t ws_size,
                              hipStream_t stream) {
    const float* x_src = (const float*)d_in[0];
    const float* W = (const float*)d_in[2];
    const int* edge_index = (const int*)d_in[3];
    const float* t = (const float*)d_in[4];

    int E = in_sizes[4];
    int N = in_sizes[1] / H;  // N_DST
    int M = in_sizes[0] / H;  // N_SRC
    const int* src = edge_index;
    const int* dst = edge_index + E;

    // ws layout (u32): base[N+1] | cursor[N] | bsum[1024] | boff[1024] | payload(int2)[E] | y[M*H]
    unsigned* base = (unsigned*)d_ws;
    unsigned* cursor = base + (size_t)N + 1;
    unsigned* bsum = cursor + N;
    unsigned* boff = bsum + 1024;
    int2* payload = (int2*)(boff + 1024);
    float* y = (float*)(payload + E);

    size_t head_bytes = (size_t)(2 * N + 2049) * 4;
    bool have_payload = (ws_size >= head_bytes + (size_t)E * 8);
    bool have_y = (ws_size >= head_bytes + (size_t)E * 8 + (size_t)M * H * 4);

    int nb = (N + 1023) / 1024;

    hipMemsetAsync(cursor, 0, (size_t)N * sizeof(unsigned), stream);

    int blocks_e = (E + 255) / 256;
    if (blocks_e > 2048) blocks_e = 2048;

    k_hist<<<1024, 256, 0, stream>>>(dst, cursor, E);
    k_scanA<<<nb, 1024, 0, stream>>>(cursor, base, bsum, N);
    k_scanB<<<1, 1024, 0, stream>>>(bsum, boff, nb);
    k_scanC<<<512, 256, 0, stream>>>(base, cursor, boff, N, E);

    if (have_y) {
        k_xform2<<<(M + 63) / 64, 256, 0, stream>>>(x_src, W, y, M);
        k_permute_part<<<2048, 256, 0, stream>>>(dst, src, t, cursor, payload, E, N);
        k_gather2y<<<4096, 256, 0, stream>>>(base, payload, y, (float*)d_out, N);
    } else if (have_payload) {
        k_permute_pack<<<blocks_e, 256, 0, stream>>>(dst, src, t, cursor, payload, E);
        k_gather_fb<<<4096, 256, 0, stream>>>(base, payload, x_src, W, (float*)d_out, N);
    } else {
        int* eidperm = (int*)payload;  // needs only E*4
        k_permute_idx<<<blocks_e, 256, 0, stream>>>(dst, cursor, eidperm, E);
        k_gather_idx<<<4096, 256, 0, stream>>>(base, eidperm, src, t, x_src, W,
                                               (float*)d_out, N);
    }
}

// Round 8
// 179.598 us; speedup vs baseline: 2.2807x; 1.1244x over previous
//
#include <hip/hip_runtime.h>
#include <math.h>

#define H 64
#define NXCD 8

typedef __attribute__((ext_vector_type(8))) short short8;
typedef __attribute__((ext_vector_type(4))) float f32x4;

__device__ inline ushort f2bf(float f) {
    union { float f; unsigned u; } v;
    v.f = f;
    unsigned r = v.u + 0x7FFFu + ((v.u >> 16) & 1u);
    return (ushort)(r >> 16);
}

// ---------- Pass 1: histogram of destinations (int4-vectorized reads) ----------
__global__ void k_hist(const int* __restrict__ dst, unsigned* __restrict__ cnt, int E) {
    int i = blockIdx.x * blockDim.x + threadIdx.x;
    int st = gridDim.x * blockDim.x;
    int E4 = E >> 2;
    const int4* d4 = (const int4*)dst;
    for (int k = i; k < E4; k += st) {
        int4 v = d4[k];
        atomicAdd(&cnt[v.x], 1u);
        atomicAdd(&cnt[v.y], 1u);
        atomicAdd(&cnt[v.z], 1u);
        atomicAdd(&cnt[v.w], 1u);
    }
    for (int k = (E4 << 2) + i; k < E; k += st) atomicAdd(&cnt[dst[k]], 1u);
}

// ---------- Hierarchical exclusive scan ----------
__global__ __launch_bounds__(1024) void k_scanA(const unsigned* __restrict__ cnt,
                                                unsigned* __restrict__ base,
                                                unsigned* __restrict__ bsum, int N) {
    __shared__ unsigned wsum[16];
    int i = blockIdx.x * 1024 + threadIdx.x;
    unsigned v = (i < N) ? cnt[i] : 0u;
    int lane = threadIdx.x & 63, w = threadIdx.x >> 6;
    unsigned x = v;
#pragma unroll
    for (int off = 1; off < 64; off <<= 1) {
        unsigned y = __shfl_up(x, off, 64);
        if (lane >= off) x += y;
    }
    if (lane == 63) wsum[w] = x;
    __syncthreads();
    if (threadIdx.x < 16) {
        unsigned s = wsum[threadIdx.x];
#pragma unroll
        for (int off = 1; off < 16; off <<= 1) {
            unsigned y = __shfl_up(s, off, 16);
            if ((threadIdx.x & 15) >= off) s += y;
        }
        wsum[threadIdx.x] = s;
    }
    __syncthreads();
    unsigned wbase = (w > 0) ? wsum[w - 1] : 0u;
    if (i < N) base[i] = wbase + x - v;
    if (threadIdx.x == 1023) bsum[blockIdx.x] = wsum[15];
}

__global__ __launch_bounds__(1024) void k_scanB(const unsigned* __restrict__ bsum,
                                                unsigned* __restrict__ boff, int nb) {
    __shared__ unsigned wsum[16];
    int i = threadIdx.x;
    unsigned v = (i < nb) ? bsum[i] : 0u;
    int lane = i & 63, w = i >> 6;
    unsigned x = v;
#pragma unroll
    for (int off = 1; off < 64; off <<= 1) {
        unsigned y = __shfl_up(x, off, 64);
        if (lane >= off) x += y;
    }
    if (lane == 63) wsum[w] = x;
    __syncthreads();
    if (i < 16) {
        unsigned s = wsum[i];
#pragma unroll
        for (int off = 1; off < 16; off <<= 1) {
            unsigned y = __shfl_up(s, off, 16);
            if ((i & 15) >= off) s += y;
        }
        wsum[i] = s;
    }
    __syncthreads();
    unsigned wbase = (w > 0) ? wsum[w - 1] : 0u;
    if (i < nb) boff[i] = wbase + x - v;
}

__global__ void k_scanC(unsigned* __restrict__ base, unsigned* __restrict__ cursor,
                        const unsigned* __restrict__ boff, int N, int E) {
    int i = blockIdx.x * blockDim.x + threadIdx.x;
    int st = gridDim.x * blockDim.x;
    for (; i < N; i += st) {
        unsigned b = base[i] + boff[i >> 10];
        base[i] = b;
        cursor[i] = b;
    }
    if (blockIdx.x == 0 && threadIdx.x == 0) base[N] = (unsigned)E;
}

// ---------- Pass 2 (fast path): XCD-partitioned CSR bucketing (verified R6/R7) ----------
__global__ void k_permute_part(const int* __restrict__ dst, const int* __restrict__ src,
                               const float* __restrict__ t, unsigned* __restrict__ cursor,
                               int2* __restrict__ payload, int E, int N) {
    const float inv = 1.0f / (0.5f + 1e-8f);
    int part = blockIdx.x & (NXCD - 1);
    int nslice = gridDim.x >> 3;
    int sblk = blockIdx.x >> 3;
    int lo = (int)((long long)part * N / NXCD);
    int hi = (int)((long long)(part + 1) * N / NXCD);
    int e0 = (int)((long long)sblk * E / nslice);
    int e1 = (int)((long long)(sblk + 1) * E / nslice);
    for (int i = e0 + threadIdx.x; i < e1; i += blockDim.x) {
        int d = dst[i];
        if (d >= lo && d < hi) {
            unsigned pos = atomicAdd(&cursor[d], 1u);
            float e = __expf(t[i] * inv);
            payload[pos] = make_int2(src[i], __float_as_int(e));
        }
    }
}

// ---------- Pass 2 (fallback): plain packing permute ----------
__global__ void k_permute_pack(const int* __restrict__ dst, const int* __restrict__ src,
                               const float* __restrict__ t, unsigned* __restrict__ cursor,
                               int2* __restrict__ payload, int E) {
    const float inv = 1.0f / (0.5f + 1e-8f);
    int i = blockIdx.x * blockDim.x + threadIdx.x;
    int st = gridDim.x * blockDim.x;
    for (; i < E; i += st) {
        unsigned pos = atomicAdd(&cursor[dst[i]], 1u);
        float e = __expf(t[i] * inv);
        payload[pos] = make_int2(src[i], __float_as_int(e));
    }
}

// ---------- Pre-transform: y(bf16) = x @ W^T via MFMA 16x16x32 bf16 ----------
// One wave per 16-row tile. Layout (m89/m225 verified convention):
//   A lane l: row l&15, k = (l>>4)*8 + j    (x rows, k-consecutive)
//   B lane l: col l&15, k = (l>>4)*8 + j    (W row c holds k-major -> B^T-stored)
//   D lane l: col l&15, row = (l>>4)*4 + reg
__global__ __launch_bounds__(256) void k_xform_mfma(const float* __restrict__ x,
                                                    const float* __restrict__ W,
                                                    ushort* __restrict__ y, int M) {
    int wid = (blockIdx.x * blockDim.x + threadIdx.x) >> 6;
    int lane = threadIdx.x & 63;
    int n0 = wid * 16;
    if (n0 >= M) return;
    int r = lane & 15, g = lane >> 4;

    short8 bfrag[4][2];
#pragma unroll
    for (int ct = 0; ct < 4; ++ct) {
#pragma unroll
        for (int kh = 0; kh < 2; ++kh) {
            const float* wp = &W[(size_t)(ct * 16 + r) * 64 + kh * 32 + g * 8];
            float4 w0 = *(const float4*)wp;
            float4 w1 = *(const float4*)(wp + 4);
            short8 bf;
            bf[0] = (short)f2bf(w0.x); bf[1] = (short)f2bf(w0.y);
            bf[2] = (short)f2bf(w0.z); bf[3] = (short)f2bf(w0.w);
            bf[4] = (short)f2bf(w1.x); bf[5] = (short)f2bf(w1.y);
            bf[6] = (short)f2bf(w1.z); bf[7] = (short)f2bf(w1.w);
            bfrag[ct][kh] = bf;
        }
    }
    int xr = n0 + r;
    if (xr >= M) xr = M - 1;
    const float* xp = &x[(size_t)xr * 64 + g * 8];
    short8 afrag[2];
#pragma unroll
    for (int kh = 0; kh < 2; ++kh) {
        float4 a0 = *(const float4*)(xp + kh * 32);
        float4 a1 = *(const float4*)(xp + kh * 32 + 4);
        short8 af;
        af[0] = (short)f2bf(a0.x); af[1] = (short)f2bf(a0.y);
        af[2] = (short)f2bf(a0.z); af[3] = (short)f2bf(a0.w);
        af[4] = (short)f2bf(a1.x); af[5] = (short)f2bf(a1.y);
        af[6] = (short)f2bf(a1.z); af[7] = (short)f2bf(a1.w);
        afrag[kh] = af;
    }
#pragma unroll
    for (int ct = 0; ct < 4; ++ct) {
        f32x4 acc = {0.f, 0.f, 0.f, 0.f};
        acc = __builtin_amdgcn_mfma_f32_16x16x32_bf16(afrag[0], bfrag[ct][0], acc, 0, 0, 0);
        acc = __builtin_amdgcn_mfma_f32_16x16x32_bf16(afrag[1], bfrag[ct][1], acc, 0, 0, 0);
#pragma unroll
        for (int q = 0; q < 4; ++q) {
            int row = n0 + g * 4 + q;
            if (row < M) y[(size_t)row * 64 + ct * 16 + r] = f2bf(acc[q]);
        }
    }
}

// ---------- Pass 3: weighted gather of bf16 y rows. 2 rows per load inst. ----------
// lane = (h = lane>>5: row-half, f = lane&31: feature pair). Uniform shfls + select.
__global__ __launch_bounds__(256) void k_gather_bf(const unsigned* __restrict__ base,
                                                   const int2* __restrict__ payload,
                                                   const unsigned* __restrict__ yb,
                                                   float* __restrict__ out, int N) {
    int lane = threadIdx.x & 63;
    int h = lane >> 5;
    int f = lane & 31;
    int wid = (blockIdx.x * blockDim.x + threadIdx.x) >> 6;
    int nw = (gridDim.x * blockDim.x) >> 6;
    for (int d = wid; d < N; d += nw) {
        unsigned r0 = base[d], r1 = base[d + 1];
        int deg = (int)(r1 - r0);
        float acc0 = 0.f, acc1 = 0.f, ssum = 0.f;
        for (int c = 0; c < deg; c += 64) {
            int j = c + lane;
            int cd = min(64, deg - c);
            float e = 0.f;
            int sidx = 0;
            if (j < deg) {
                int2 p = payload[r0 + j];
                sidx = p.x;
                e = __int_as_float(p.y);
            }
            float cs = e;
#pragma unroll
            for (int off = 32; off >= 1; off >>= 1) cs += __shfl_xor(cs, off, 64);
            ssum += cs;
            for (int q = 0; q < cd; q += 16) {
                float al[8];
                int sl[8];
#pragma unroll
                for (int u = 0; u < 8; ++u) {
                    int ra = q + 2 * u, rb = ra + 1;
                    float a0 = __shfl(e, ra, 64), a1 = __shfl(e, rb, 64);
                    int s0 = __shfl(sidx, ra, 64), s1 = __shfl(sidx, rb, 64);
                    int rr = ra + h;  // this lane's row
                    bool ok = (rr < cd);
                    al[u] = ok ? (h ? a1 : a0) : 0.f;
                    sl[u] = ok ? (h ? s1 : s0) : 0;
                }
                unsigned pv[8];
#pragma unroll
                for (int u = 0; u < 8; ++u) pv[u] = yb[(size_t)sl[u] * 32 + f];
#pragma unroll
                for (int u = 0; u < 8; ++u) {
                    float lo = __uint_as_float(pv[u] << 16);
                    float hi = __uint_as_float(pv[u] & 0xFFFF0000u);
                    acc0 = fmaf(al[u], lo, acc0);
                    acc1 = fmaf(al[u], hi, acc1);
                }
            }
        }
        acc0 += __shfl_xor(acc0, 32, 64);
        acc1 += __shfl_xor(acc1, 32, 64);
        float rs = 1.0f / (ssum + 1e-16f);
        if (h == 0) {
            float2 o = make_float2(acc0 * rs, acc1 * rs);
            *(float2*)&out[(size_t)d * H + f * 2] = o;
        }
    }
}

// ---------- Fallback (verified R3/R5): gather x_src with fused W epilogue ----------
__global__ __launch_bounds__(256) void k_gather_fb(const unsigned* __restrict__ base,
                                                   const int2* __restrict__ payload,
                                                   const float* __restrict__ x_src,
                                                   const float* __restrict__ W,
                                                   float* __restrict__ out, int N) {
    __shared__ float wt[H * H];
    for (int idx = threadIdx.x; idx < H * H; idx += blockDim.x) {
        int j = idx >> 6, k = idx & 63;
        wt[k * H + j] = W[idx];
    }
    __syncthreads();
    int lane = threadIdx.x & 63;
    int wid = (blockIdx.x * blockDim.x + threadIdx.x) >> 6;
    int nw = (gridDim.x * blockDim.x) >> 6;
    for (int d = wid; d < N; d += nw) {
        unsigned r0 = base[d], r1 = base[d + 1];
        int deg = (int)(r1 - r0);
        float acc = 0.0f, ssum = 0.0f;
        for (int c = 0; c < deg; c += 64) {
            int j = c + lane;
            int cd = min(64, deg - c);
            float e = 0.0f;
            int sidx = 0;
            if (j < deg) {
                int2 p = payload[r0 + j];
                sidx = p.x;
                e = __int_as_float(p.y);
            }
            float cs = e;
#pragma unroll
            for (int off = 32; off >= 1; off >>= 1) cs += __shfl_xor(cs, off, 64);
            ssum += cs;
            for (int q = 0; q < cd; q += 8) {
                float a[8];
                int sv[8];
                float v[8];
#pragma unroll
                for (int u = 0; u < 8; ++u) {
                    a[u] = __shfl(e, q + u, 64);
                    sv[u] = __shfl(sidx, q + u, 64);
                }
#pragma unroll
                for (int u = 0; u < 8; ++u) v[u] = x_src[(size_t)sv[u] * H + lane];
#pragma unroll
                for (int u = 0; u < 8; ++u) acc = fmaf(a[u], v[u], acc);
            }
        }
        acc *= 1.0f / (ssum + 1e-16f);
        float o = 0.0f;
#pragma unroll
        for (int k = 0; k < H; ++k) o = fmaf(__shfl(acc, k, 64), wt[k * H + lane], o);
        out[(size_t)d * H + lane] = o;
    }
}

extern "C" void kernel_launch(void* const* d_in, const int* in_sizes, int n_in,
                              void* d_out, int out_size, void* d_ws, size_t ws_size,
                              hipStream_t stream) {
    const float* x_src = (const float*)d_in[0];
    const float* W = (const float*)d_in[2];
    const int* edge_index = (const int*)d_in[3];
    const float* t = (const float*)d_in[4];

    int E = in_sizes[4];
    int N = in_sizes[1] / H;  // N_DST
    int M = in_sizes[0] / H;  // N_SRC
    const int* src = edge_index;
    const int* dst = edge_index + E;

    // ws layout (u32): base[N+1] | cursor[N] | bsum[1024] | boff[1024] | payload(int2)[E] | y_bf16[M*H]
    unsigned* base = (unsigned*)d_ws;
    unsigned* cursor = base + (size_t)N + 1;
    unsigned* bsum = cursor + N;
    unsigned* boff = bsum + 1024;
    int2* payload = (int2*)(boff + 1024);
    ushort* y = (ushort*)(payload + E);

    size_t head_bytes = (size_t)(2 * N + 2049) * 4;
    bool have_payload = (ws_size >= head_bytes + (size_t)E * 8);
    bool have_y = (ws_size >= head_bytes + (size_t)E * 8 + (size_t)M * H * 2);

    int nb = (N + 1023) / 1024;

    hipMemsetAsync(cursor, 0, (size_t)N * sizeof(unsigned), stream);

    int blocks_e = (E + 255) / 256;
    if (blocks_e > 2048) blocks_e = 2048;

    k_hist<<<1024, 256, 0, stream>>>(dst, cursor, E);
    k_scanA<<<nb, 1024, 0, stream>>>(cursor, base, bsum, N);
    k_scanB<<<1, 1024, 0, stream>>>(bsum, boff, nb);
    k_scanC<<<512, 256, 0, stream>>>(base, cursor, boff, N, E);

    if (have_y) {
        int xblocks = ((M + 15) / 16 * 64 + 255) / 256;
        k_xform_mfma<<<xblocks, 256, 0, stream>>>(x_src, W, y, M);
        k_permute_part<<<2048, 256, 0, stream>>>(dst, src, t, cursor, payload, E, N);
        k_gather_bf<<<4096, 256, 0, stream>>>(base, payload, (const unsigned*)y,
                                              (float*)d_out, N);
    } else if (have_payload) {
        k_permute_pack<<<blocks_e, 256, 0, stream>>>(dst, src, t, cursor, payload, E);
        k_gather_fb<<<4096, 256, 0, stream>>>(base, payload, x_src, W, (float*)d_out, N);
    } else {
        k_permute_pack<<<blocks_e, 256, 0, stream>>>(dst, src, t, cursor, payload, E);
        k_gather_fb<<<4096, 256, 0, stream>>>(base, payload, x_src, W, (float*)d_out, N);
    }
}

// Round 10
// 166.212 us; speedup vs baseline: 2.4643x; 1.0805x over previous
//
#include <hip/hip_runtime.h>
#include <math.h>

#define H 64
#define NXCD 8

typedef __attribute__((ext_vector_type(8))) short short8;
typedef __attribute__((ext_vector_type(4))) float f32x4;

__device__ inline ushort f2bf(float f) {
    union { float f; unsigned u; } v;
    v.f = f;
    unsigned r = v.u + 0x7FFFu + ((v.u >> 16) & 1u);
    return (ushort)(r >> 16);
}

// ---------- Pass 1: histogram of destinations (int4-vectorized reads) ----------
__global__ void k_hist(const int* __restrict__ dst, unsigned* __restrict__ cnt, int E) {
    int i = blockIdx.x * blockDim.x + threadIdx.x;
    int st = gridDim.x * blockDim.x;
    int E4 = E >> 2;
    const int4* d4 = (const int4*)dst;
    for (int k = i; k < E4; k += st) {
        int4 v = d4[k];
        atomicAdd(&cnt[v.x], 1u);
        atomicAdd(&cnt[v.y], 1u);
        atomicAdd(&cnt[v.z], 1u);
        atomicAdd(&cnt[v.w], 1u);
    }
    for (int k = (E4 << 2) + i; k < E; k += st) atomicAdd(&cnt[dst[k]], 1u);
}

// ---------- Hierarchical exclusive scan ----------
__global__ __launch_bounds__(1024) void k_scanA(const unsigned* __restrict__ cnt,
                                                unsigned* __restrict__ base,
                                                unsigned* __restrict__ bsum, int N) {
    __shared__ unsigned wsum[16];
    int i = blockIdx.x * 1024 + threadIdx.x;
    unsigned v = (i < N) ? cnt[i] : 0u;
    int lane = threadIdx.x & 63, w = threadIdx.x >> 6;
    unsigned x = v;
#pragma unroll
    for (int off = 1; off < 64; off <<= 1) {
        unsigned y = __shfl_up(x, off, 64);
        if (lane >= off) x += y;
    }
    if (lane == 63) wsum[w] = x;
    __syncthreads();
    if (threadIdx.x < 16) {
        unsigned s = wsum[threadIdx.x];
#pragma unroll
        for (int off = 1; off < 16; off <<= 1) {
            unsigned y = __shfl_up(s, off, 16);
            if ((threadIdx.x & 15) >= off) s += y;
        }
        wsum[threadIdx.x] = s;
    }
    __syncthreads();
    unsigned wbase = (w > 0) ? wsum[w - 1] : 0u;
    if (i < N) base[i] = wbase + x - v;
    if (threadIdx.x == 1023) bsum[blockIdx.x] = wsum[15];
}

__global__ __launch_bounds__(1024) void k_scanB(const unsigned* __restrict__ bsum,
                                                unsigned* __restrict__ boff, int nb) {
    __shared__ unsigned wsum[16];
    int i = threadIdx.x;
    unsigned v = (i < nb) ? bsum[i] : 0u;
    int lane = i & 63, w = i >> 6;
    unsigned x = v;
#pragma unroll
    for (int off = 1; off < 64; off <<= 1) {
        unsigned y = __shfl_up(x, off, 64);
        if (lane >= off) x += y;
    }
    if (lane == 63) wsum[w] = x;
    __syncthreads();
    if (i < 16) {
        unsigned s = wsum[i];
#pragma unroll
        for (int off = 1; off < 16; off <<= 1) {
            unsigned y = __shfl_up(s, off, 16);
            if ((i & 15) >= off) s += y;
        }
        wsum[i] = s;
    }
    __syncthreads();
    unsigned wbase = (w > 0) ? wsum[w - 1] : 0u;
    if (i < nb) boff[i] = wbase + x - v;
}

__global__ void k_scanC(unsigned* __restrict__ base, unsigned* __restrict__ cursor,
                        const unsigned* __restrict__ boff, int N, int E) {
    int i = blockIdx.x * blockDim.x + threadIdx.x;
    int st = gridDim.x * blockDim.x;
    for (; i < N; i += st) {
        unsigned b = base[i] + boff[i >> 10];
        base[i] = b;
        cursor[i] = b;
    }
    if (blockIdx.x == 0 && threadIdx.x == 0) base[N] = (unsigned)E;
}

// ---------- Pass 2 (fast path): XCD-partitioned CSR bucketing (verified R6-R8) ----------
__global__ void k_permute_part(const int* __restrict__ dst, const int* __restrict__ src,
                               const float* __restrict__ t, unsigned* __restrict__ cursor,
                               int2* __restrict__ payload, int E, int N) {
    const float inv = 1.0f / (0.5f + 1e-8f);
    int part = blockIdx.x & (NXCD - 1);
    int nslice = gridDim.x >> 3;
    int sblk = blockIdx.x >> 3;
    int lo = (int)((long long)part * N / NXCD);
    int hi = (int)((long long)(part + 1) * N / NXCD);
    int e0 = (int)((long long)sblk * E / nslice);
    int e1 = (int)((long long)(sblk + 1) * E / nslice);
    for (int i = e0 + threadIdx.x; i < e1; i += blockDim.x) {
        int d = dst[i];
        if (d >= lo && d < hi) {
            unsigned pos = atomicAdd(&cursor[d], 1u);
            float e = __expf(t[i] * inv);
            payload[pos] = make_int2(src[i], __float_as_int(e));
        }
    }
}

// ---------- Pass 2 (fallback): plain packing permute ----------
__global__ void k_permute_pack(const int* __restrict__ dst, const int* __restrict__ src,
                               const float* __restrict__ t, unsigned* __restrict__ cursor,
                               int2* __restrict__ payload, int E) {
    const float inv = 1.0f / (0.5f + 1e-8f);
    int i = blockIdx.x * blockDim.x + threadIdx.x;
    int st = gridDim.x * blockDim.x;
    for (; i < E; i += st) {
        unsigned pos = atomicAdd(&cursor[dst[i]], 1u);
        float e = __expf(t[i] * inv);
        payload[pos] = make_int2(src[i], __float_as_int(e));
    }
}

// ---------- Pre-transform: y(bf16) = x @ W^T via MFMA 16x16x32 bf16 (verified R8) ----------
__global__ __launch_bounds__(256) void k_xform_mfma(const float* __restrict__ x,
                                                    const float* __restrict__ W,
                                                    ushort* __restrict__ y, int M) {
    int wid = (blockIdx.x * blockDim.x + threadIdx.x) >> 6;
    int lane = threadIdx.x & 63;
    int n0 = wid * 16;
    if (n0 >= M) return;
    int r = lane & 15, g = lane >> 4;

    short8 bfrag[4][2];
#pragma unroll
    for (int ct = 0; ct < 4; ++ct) {
#pragma unroll
        for (int kh = 0; kh < 2; ++kh) {
            const float* wp = &W[(size_t)(ct * 16 + r) * 64 + kh * 32 + g * 8];
            float4 w0 = *(const float4*)wp;
            float4 w1 = *(const float4*)(wp + 4);
            short8 bf;
            bf[0] = (short)f2bf(w0.x); bf[1] = (short)f2bf(w0.y);
            bf[2] = (short)f2bf(w0.z); bf[3] = (short)f2bf(w0.w);
            bf[4] = (short)f2bf(w1.x); bf[5] = (short)f2bf(w1.y);
            bf[6] = (short)f2bf(w1.z); bf[7] = (short)f2bf(w1.w);
            bfrag[ct][kh] = bf;
        }
    }
    int xr = n0 + r;
    if (xr >= M) xr = M - 1;
    const float* xp = &x[(size_t)xr * 64 + g * 8];
    short8 afrag[2];
#pragma unroll
    for (int kh = 0; kh < 2; ++kh) {
        float4 a0 = *(const float4*)(xp + kh * 32);
        float4 a1 = *(const float4*)(xp + kh * 32 + 4);
        short8 af;
        af[0] = (short)f2bf(a0.x); af[1] = (short)f2bf(a0.y);
        af[2] = (short)f2bf(a0.z); af[3] = (short)f2bf(a0.w);
        af[4] = (short)f2bf(a1.x); af[5] = (short)f2bf(a1.y);
        af[6] = (short)f2bf(a1.z); af[7] = (short)f2bf(a1.w);
        afrag[kh] = af;
    }
#pragma unroll
    for (int ct = 0; ct < 4; ++ct) {
        f32x4 acc = {0.f, 0.f, 0.f, 0.f};
        acc = __builtin_amdgcn_mfma_f32_16x16x32_bf16(afrag[0], bfrag[ct][0], acc, 0, 0, 0);
        acc = __builtin_amdgcn_mfma_f32_16x16x32_bf16(afrag[1], bfrag[ct][1], acc, 0, 0, 0);
#pragma unroll
        for (int q = 0; q < 4; ++q) {
            int row = n0 + g * 4 + q;
            if (row < M) y[(size_t)row * 64 + ct * 16 + r] = f2bf(acc[q]);
        }
    }
}

// ---------- Pass 3: weighted gather, 4 dests/wave, 16 lanes/dest, no shfls ----------
// Lane (g = lane>>4: dest slot, f = lane&15: 4-feature chunk). Payload entries are
// loaded uniformly within the 16-lane group (cache broadcast); ssum needs no reduce
// because every lane accumulates the identical scalars.
__global__ __launch_bounds__(256) void k_gather4(const unsigned* __restrict__ base,
                                                 const long long* __restrict__ payload,
                                                 const uint2* __restrict__ y2,
                                                 float* __restrict__ out, int N) {
    int tid = blockIdx.x * blockDim.x + threadIdx.x;
    int lane = threadIdx.x & 63;
    int g = lane >> 4, f = lane & 15;
    int d = (tid >> 6) * 4 + g;
    if (d >= N) return;
    unsigned r0 = base[d], r1 = base[d + 1];
    int deg = (int)(r1 - r0);
    float acc0 = 0.f, acc1 = 0.f, acc2 = 0.f, acc3 = 0.f, ssum = 0.f;
    for (int it = 0; it < deg; it += 4) {
        float e[4];
        int s[4];
#pragma unroll
        for (int k2 = 0; k2 < 4; ++k2) {
            // memory-safe overread: payload region is followed by the y region in ws
            long long pl = __builtin_nontemporal_load(&payload[r0 + it + k2]);
            bool ok = (it + k2) < deg;
            e[k2] = ok ? __int_as_float((int)(pl >> 32)) : 0.f;
            s[k2] = ok ? (int)(pl & 0xFFFFFFFFll) : 0;
            ssum += e[k2];
        }
        uint2 v[4];
#pragma unroll
        for (int k2 = 0; k2 < 4; ++k2) v[k2] = y2[(size_t)s[k2] * 16 + f];
#pragma unroll
        for (int k2 = 0; k2 < 4; ++k2) {
            float x0 = __uint_as_float(v[k2].x << 16);
            float x1 = __uint_as_float(v[k2].x & 0xFFFF0000u);
            float x2 = __uint_as_float(v[k2].y << 16);
            float x3 = __uint_as_float(v[k2].y & 0xFFFF0000u);
            acc0 = fmaf(e[k2], x0, acc0);
            acc1 = fmaf(e[k2], x1, acc1);
            acc2 = fmaf(e[k2], x2, acc2);
            acc3 = fmaf(e[k2], x3, acc3);
        }
    }
    float rs = 1.0f / (ssum + 1e-16f);
    f32x4 o = {acc0 * rs, acc1 * rs, acc2 * rs, acc3 * rs};
    __builtin_nontemporal_store(o, (f32x4*)&out[(size_t)d * H + f * 4]);
}

// ---------- Fallback (verified R3/R5): gather x_src with fused W epilogue ----------
__global__ __launch_bounds__(256) void k_gather_fb(const unsigned* __restrict__ base,
                                                   const int2* __restrict__ payload,
                                                   const float* __restrict__ x_src,
                                                   const float* __restrict__ W,
                                                   float* __restrict__ out, int N) {
    __shared__ float wt[H * H];
    for (int idx = threadIdx.x; idx < H * H; idx += blockDim.x) {
        int j = idx >> 6, k = idx & 63;
        wt[k * H + j] = W[idx];
    }
    __syncthreads();
    int lane = threadIdx.x & 63;
    int wid = (blockIdx.x * blockDim.x + threadIdx.x) >> 6;
    int nw = (gridDim.x * blockDim.x) >> 6;
    for (int d = wid; d < N; d += nw) {
        unsigned r0 = base[d], r1 = base[d + 1];
        int deg = (int)(r1 - r0);
        float acc = 0.0f, ssum = 0.0f;
        for (int c = 0; c < deg; c += 64) {
            int j = c + lane;
            int cd = min(64, deg - c);
            float e = 0.0f;
            int sidx = 0;
            if (j < deg) {
                int2 p = payload[r0 + j];
                sidx = p.x;
                e = __int_as_float(p.y);
            }
            float cs = e;
#pragma unroll
            for (int off = 32; off >= 1; off >>= 1) cs += __shfl_xor(cs, off, 64);
            ssum += cs;
            for (int q = 0; q < cd; q += 8) {
                float a[8];
                int sv[8];
                float v[8];
#pragma unroll
                for (int u = 0; u < 8; ++u) {
                    a[u] = __shfl(e, q + u, 64);
                    sv[u] = __shfl(sidx, q + u, 64);
                }
#pragma unroll
                for (int u = 0; u < 8; ++u) v[u] = x_src[(size_t)sv[u] * H + lane];
#pragma unroll
                for (int u = 0; u < 8; ++u) acc = fmaf(a[u], v[u], acc);
            }
        }
        acc *= 1.0f / (ssum + 1e-16f);
        float o = 0.0f;
#pragma unroll
        for (int k = 0; k < H; ++k) o = fmaf(__shfl(acc, k, 64), wt[k * H + lane], o);
        out[(size_t)d * H + lane] = o;
    }
}

extern "C" void kernel_launch(void* const* d_in, const int* in_sizes, int n_in,
                              void* d_out, int out_size, void* d_ws, size_t ws_size,
                              hipStream_t stream) {
    const float* x_src = (const float*)d_in[0];
    const float* W = (const float*)d_in[2];
    const int* edge_index = (const int*)d_in[3];
    const float* t = (const float*)d_in[4];

    int E = in_sizes[4];
    int N = in_sizes[1] / H;  // N_DST
    int M = in_sizes[0] / H;  // N_SRC
    const int* src = edge_index;
    const int* dst = edge_index + E;

    // ws layout: base[N+1] | cursor[N] | bsum[1024] | boff[1024] | payload(int2,8B-aligned)[E] | y bf16 (16B-aligned)[M*H]
    unsigned* base = (unsigned*)d_ws;
    unsigned* cursor = base + (size_t)N + 1;
    unsigned* bsum = cursor + N;
    unsigned* boff = bsum + 1024;
    size_t pay_off = (((size_t)(2 * N + 2049)) * 4 + 7) & ~(size_t)7;
    int2* payload = (int2*)((char*)d_ws + pay_off);
    size_t y_off = (pay_off + (size_t)E * 8 + 15) & ~(size_t)15;
    ushort* y = (ushort*)((char*)d_ws + y_off);

    bool have_payload = (ws_size >= pay_off + (size_t)E * 8 + 32);
    bool have_y = (ws_size >= y_off + (size_t)M * H * 2);

    int nb = (N + 1023) / 1024;

    hipMemsetAsync(cursor, 0, (size_t)N * sizeof(unsigned), stream);

    int blocks_e = (E + 255) / 256;
    if (blocks_e > 2048) blocks_e = 2048;

    k_hist<<<1024, 256, 0, stream>>>(dst, cursor, E);
    k_scanA<<<nb, 1024, 0, stream>>>(cursor, base, bsum, N);
    k_scanB<<<1, 1024, 0, stream>>>(bsum, boff, nb);
    k_scanC<<<512, 256, 0, stream>>>(base, cursor, boff, N, E);

    if (have_y) {
        int xblocks = ((M + 15) / 16 * 64 + 255) / 256;
        k_xform_mfma<<<xblocks, 256, 0, stream>>>(x_src, W, y, M);
        k_permute_part<<<2048, 256, 0, stream>>>(dst, src, t, cursor, payload, E, N);
        int gblocks = (N + 15) / 16;  // 4 waves/block, 4 dests/wave
        k_gather4<<<gblocks, 256, 0, stream>>>(base, (const long long*)payload,
                                               (const uint2*)y, (float*)d_out, N);
    } else if (have_payload) {
        k_permute_pack<<<blocks_e, 256, 0, stream>>>(dst, src, t, cursor, payload, E);
        k_gather_fb<<<4096, 256, 0, stream>>>(base, payload, x_src, W, (float*)d_out, N);
    } else {
        k_permute_pack<<<blocks_e, 256, 0, stream>>>(dst, src, t, cursor, payload, E);
        k_gather_fb<<<4096, 256, 0, stream>>>(base, payload, x_src, W, (float*)d_out, N);
    }
}